// Round 15
// baseline (188.767 us; speedup 1.0000x reference)
//
#include <hip/hip_runtime.h>

typedef __attribute__((ext_vector_type(8))) short short8;
typedef __attribute__((ext_vector_type(4))) float f32x4;
typedef __attribute__((ext_vector_type(2))) float f32x2;
typedef __attribute__((ext_vector_type(4))) ushort u16x4;

constexpr int NN = 10000;
constexpr int NE = 160000;
constexpr int NT = NE / 16;                    // 10000 edge-tiles
constexpr int TPSTR = 48;                      // tp row stride (192 B = 3 lines)
constexpr int GBLK = 625;                      // gather blocks (625*16 = NN)
constexpr float EPSV = 1e-5f;
constexpr float INV3 = 0.57735026918962576f;   // 1/sqrt(3)
constexpr float ALPHA = 0.20412414523193152f;  // 1/sqrt(16+8)

__device__ __forceinline__ ushort f2bf(float x) {
  unsigned u = __float_as_uint(x);
  u += 0x7fffu + ((u >> 16) & 1u);
  return (ushort)(u >> 16);
}
__device__ __forceinline__ float bf2f(ushort u) {
  return __uint_as_float(((unsigned)u) << 16);
}
__device__ __forceinline__ f32x4 mfma16(short8 a, short8 b, f32x4 c) {
  return __builtin_amdgcn_mfma_f32_16x16x32_bf16(a, b, c, 0, 0, 0);
}

template <typename T> struct TPS;
template <> struct TPS<float> {
  static __device__ __forceinline__ void st4(float* p, f32x4 v) { *(f32x4*)p = v; }
  static __device__ __forceinline__ float ld(const float* p) { return *p; }
};
template <> struct TPS<ushort> {
  static __device__ __forceinline__ void st4(ushort* p, f32x4 v) {
    u16x4 o;
#pragma unroll
    for (int j = 0; j < 4; ++j) o[j] = f2bf(v[j]);
    *(u16x4*)p = o;
  }
  static __device__ __forceinline__ float ld(const ushort* p) { return bf2f(*p); }
};

// ---------------- K1: mlp1 + merged aux (W2 prep, deg/stats/done zero) ----------------
// blocks [0,2500): h = relu(ef@W1+b1) -> bf16 h-frags (verified body)
// blocks [2500,2518): W2 -> bf16 A-frag layout (4 units/block)
// blocks [2518,2558): zero deg[NN] + stats block (48 ints incl done counter)
constexpr int MLP1_MAIN = 2500;
constexpr int MLP1_GRID = MLP1_MAIN + 18 + 40;

__global__ __launch_bounds__(256) void mlp1_kernel(
    const float* __restrict__ ef, const float* __restrict__ w1,
    const float* __restrict__ b1, short8* __restrict__ hfrag,
    float* __restrict__ efout, int do_copy,
    const float* __restrict__ w2, short8* __restrict__ w2bf,
    int* __restrict__ degz)
{
  __shared__ short8 w1f[512];
  __shared__ ushort hlds[4][16 * 72];

  if (blockIdx.x >= MLP1_MAIN) {
    int aux = blockIdx.x - MLP1_MAIN;
    if (aux < 18) {                 // W2 prep: unit = 2*jt + kc, 72 units
      int unit = aux * 4 + (threadIdx.x >> 6);
      int lane = threadIdx.x & 63;
      int jt = unit >> 1, kc = unit & 1;
      int g = lane >> 4, c = lane & 15;
      short8 v;
#pragma unroll
      for (int j = 0; j < 8; ++j)
        v[j] = (short)f2bf(w2[(kc * 32 + 8 * g + j) * 576 + jt * 16 + c]);
      w2bf[(jt * 2 + kc) * 64 + lane] = v;
    } else {                        // zero deg + stats/done region
      int idx = (aux - 18) * 256 + threadIdx.x;
      if (idx < NN + 48) degz[idx] = 0;
    }
    return;
  }

  for (int t = threadIdx.x; t < 512; t += 256) {
    int tile = t >> 6, l = t & 63;
    int nt = tile >> 1, kc = tile & 1;
    int gg = l >> 4, cc = l & 15;
    short8 v;
#pragma unroll
    for (int j = 0; j < 8; ++j)
      v[j] = (short)f2bf(w1[(kc * 32 + 8 * gg + j) * 64 + nt * 16 + cc]);
    w1f[t] = v;
  }
  __syncthreads();

  const int lane = threadIdx.x & 63, wid = threadIdx.x >> 6;
  const int g = lane >> 4, c = lane & 15;
  const long tile = (long)blockIdx.x * 4 + wid;
  const long ebase = tile * 16;

  short8 af[2];
  const float* rowp = ef + (ebase + c) * 64;
#pragma unroll
  for (int kc = 0; kc < 2; ++kc) {
    const f32x4* p = (const f32x4*)(rowp + kc * 32 + 8 * g);
    f32x4 lo = p[0], hi = p[1];
    if (do_copy) {
      f32x4* q = (f32x4*)(efout + (ebase + c) * 64 + kc * 32 + 8 * g);
      q[0] = lo; q[1] = hi;
    }
    short8 v;
#pragma unroll
    for (int j = 0; j < 4; ++j) { v[j] = (short)f2bf(lo[j]); v[4 + j] = (short)f2bf(hi[j]); }
    af[kc] = v;
  }

  f32x4 acc[4] = {};
#pragma unroll
  for (int nt = 0; nt < 4; ++nt)
#pragma unroll
    for (int kc = 0; kc < 2; ++kc)
      acc[nt] = mfma16(af[kc], w1f[(nt * 2 + kc) * 64 + lane], acc[nt]);

#pragma unroll
  for (int nt = 0; nt < 4; ++nt) {
    float bv = b1[nt * 16 + c];
#pragma unroll
    for (int q = 0; q < 4; ++q) {
      float h = fmaxf(acc[nt][q] + bv, 0.f);
      hlds[wid][(4 * g + q) * 72 + nt * 16 + c] = f2bf(h);
    }
  }
#pragma unroll
  for (int kc = 0; kc < 2; ++kc) {
    short8 hv = *(const short8*)&hlds[wid][c * 72 + kc * 32 + 8 * g];
    hfrag[(tile * 2 + kc) * 64 + lane] = hv;
  }
}

// ---------------- K2: split conv -- role A (out0) / role B (out1) by blockIdx ----------------
// r14 post-mortem: 110.8 KB LDS -> 1 block/CU (17% occ) was conv's limiter.
// Split by OUTPUT: A = w00+w11 -> tp[0..15] (W2 jt 0..23, coef a0/a1 only,
// no shfl); B = w01+w10 -> tp[16..39] (W2 jt 24..35, raw x0/x1). Max LDS
// 63.5 KB -> 2 blocks/CU. Arithmetic order identical to r14 body.
constexpr int GA = 320, GB = 192;              // grid split (LDS-cycle balanced)
constexpr int CSTRA = 28;                      // a0[16] + a1[8] + pad
constexpr int CSTRB = 44;                      // x0[16] + x1[24] + pad
constexpr unsigned SMA_W2 = 3072 * 16;         // 49152 B (jt 0..23)
constexpr unsigned SMA_B2 = 384 * 4;
constexpr unsigned SMA_SCR = 8 * 16 * CSTRA * 4;   // 14336 B
constexpr unsigned SM_AB = SMA_W2 + SMA_B2 + SMA_SCR;  // 65024 B (role max)
constexpr unsigned SMB_W2 = 1536 * 16;         // 24576 B (jt 24..35)
constexpr unsigned SMB_B2 = 192 * 4;

template <typename T>
__global__ __launch_bounds__(512) void conv_kernel(
    const short8* __restrict__ hfrag, const short8* __restrict__ w2bf,
    const float* __restrict__ b2, const float* __restrict__ nf,
    const float* __restrict__ sh, const int* __restrict__ ei,
    const int* __restrict__ perm, T* __restrict__ tp)
{
  extern __shared__ char smem[];
  const int tid = threadIdx.x;
  const int lane = tid & 63, wid = tid >> 6;
  const int g = lane >> 4, c = lane & 15;
  const int gh = g >> 1;
  const int e = lane >> 2, part = lane & 3;

  if (blockIdx.x < GA) {
    // ---------------- role A: out0 = (a0 + a1) . W2[:, 0:384] ----------------
    short8* w2l = (short8*)smem;
    float* b2l = (float*)(smem + SMA_W2);
    float* scrall = (float*)(smem + SMA_W2 + SMA_B2);
    for (int i = tid; i < 3072; i += 512) w2l[i] = w2bf[i];
    for (int i = tid; i < 384; i += 512) b2l[i] = b2[i];
    __syncthreads();
    float* scr = scrall + wid * (16 * CSTRA);

    for (int t = blockIdx.x * 8 + wid; t < NT; t += GA * 8) {
      {  // stage: a0[u] = sh0*x0[u]; a1[u] = inv3*(x1[u].sh1)  (4 lanes/edge)
        const int ege = t * 16 + e;
        const float* __restrict__ src = nf + (size_t)ei[ege] * 40;
        const f32x4 sv = *(const f32x4*)(sh + (size_t)ege * 4);
        float* ce = scr + e * CSTRA;
        f32x4 v0 = *(const f32x4*)(src + part * 4);
        f32x4 a0;
#pragma unroll
        for (int q = 0; q < 4; ++q) a0[q] = sv[0] * v0[q];
        *(f32x4*)(ce + 4 * part) = a0;
        const f32x2 q0 = *(const f32x2*)(src + 16 + 6 * part);
        const f32x2 q1 = *(const f32x2*)(src + 18 + 6 * part);
        const f32x2 q2 = *(const f32x2*)(src + 20 + 6 * part);
        ce[16 + 2 * part]     = INV3 * (q0.x * sv[1] + q0.y * sv[2] + q1.x * sv[3]);
        ce[16 + 2 * part + 1] = INV3 * (q1.y * sv[1] + q2.x * sv[2] + q2.y * sv[3]);
      }
      const short8 h0 = hfrag[(size_t)(t * 2 + 0) * 64 + lane];
      const short8 h1 = hfrag[(size_t)(t * 2 + 1) * 64 + lane];
      const float* __restrict__ cc = scr + c * CSTRA;
      f32x4 acc = {0.f, 0.f, 0.f, 0.f};
#pragma unroll
      for (int jt = 0; jt < 24; ++jt) {
        f32x4 d = *(const f32x4*)&b2l[jt * 16 + 4 * g];
        d = mfma16(w2l[(jt * 2 + 0) * 64 + lane], h0, d);
        d = mfma16(w2l[(jt * 2 + 1) * 64 + lane], h1, d);
        float a = cc[jt];
#pragma unroll
        for (int q = 0; q < 4; ++q) acc[q] = fmaf(a, d[q], acc[q]);
      }
      const int eg = t * 16 + c;
      T* tpr = tp + (size_t)perm[eg] * TPSTR;
      f32x4 o0;
#pragma unroll
      for (int q = 0; q < 4; ++q) o0[q] = ALPHA * acc[q];
      TPS<T>::st4(tpr + 4 * g, o0);
    }
  } else {
    // ---------------- role B: out1 from w01 (x0) + w10 (x1) ----------------
    short8* w2l = (short8*)smem;
    float* b2l = (float*)(smem + SMB_W2);
    float* scrall = (float*)(smem + SMB_W2 + SMB_B2);
    for (int i = tid; i < 1536; i += 512) w2l[i] = w2bf[3072 + i];
    for (int i = tid; i < 192; i += 512) b2l[i] = b2[384 + i];
    __syncthreads();
    float* scr = scrall + wid * (16 * CSTRB);

    for (int t = (blockIdx.x - GA) * 8 + wid; t < NT; t += GB * 8) {
      {  // stage raw x0 [0..15], x1 flat [16..39]
        const int ege = t * 16 + e;
        const float* __restrict__ src = nf + (size_t)ei[ege] * 40;
        float* ce = scr + e * CSTRB;
        *(f32x4*)(ce + 4 * part)      = *(const f32x4*)(src + part * 4);
        *(f32x4*)(ce + 16 + 4 * part) = *(const f32x4*)(src + 16 + part * 4);
        if (part < 2)
          *(f32x4*)(ce + 32 + 4 * part) = *(const f32x4*)(src + 32 + part * 4);
      }
      const short8 h0 = hfrag[(size_t)(t * 2 + 0) * 64 + lane];
      const short8 h1 = hfrag[(size_t)(t * 2 + 1) * 64 + lane];
      const float* __restrict__ cc = scr + c * CSTRB;
      f32x4 c0acc = {0.f, 0.f, 0.f, 0.f};
      f32x4 c1acc[3] = {};
#pragma unroll
      for (int j2 = 0; j2 < 8; ++j2) {       // w01: u = 2*j2+gh
        f32x4 d = *(const f32x4*)&b2l[j2 * 16 + 4 * g];
        d = mfma16(w2l[(j2 * 2 + 0) * 64 + lane], h0, d);
        d = mfma16(w2l[(j2 * 2 + 1) * 64 + lane], h1, d);
        float a = cc[2 * j2 + gh];
#pragma unroll
        for (int q = 0; q < 4; ++q) c0acc[q] = fmaf(a, d[q], c0acc[q]);
      }
#pragma unroll
      for (int j2 = 8; j2 < 12; ++j2) {      // w10: u = 2*(j2-8)+gh
        f32x4 d = *(const f32x4*)&b2l[j2 * 16 + 4 * g];
        d = mfma16(w2l[(j2 * 2 + 0) * 64 + lane], h0, d);
        d = mfma16(w2l[(j2 * 2 + 1) * 64 + lane], h1, d);
        const int ub = 16 + 3 * (2 * (j2 - 8) + gh);
#pragma unroll
        for (int i = 0; i < 3; ++i) {
          float a = cc[ub + i];
#pragma unroll
          for (int q = 0; q < 4; ++q) c1acc[i][q] = fmaf(a, d[q], c1acc[i][q]);
        }
      }
#pragma unroll
      for (int q = 0; q < 4; ++q) c0acc[q] += __shfl_xor(c0acc[q], 32);
#pragma unroll
      for (int i = 0; i < 3; ++i)
#pragma unroll
        for (int q = 0; q < 4; ++q) c1acc[i][q] += __shfl_xor(c1acc[i][q], 32);

      const int eg = t * 16 + c;
      const f32x4 shv = *(const f32x4*)(sh + (size_t)eg * 4);
      T* tpr = tp + (size_t)perm[eg] * TPSTR;
      if (g < 2) {
        float wv[12];
#pragma unroll
        for (int q = 0; q < 4; ++q)
#pragma unroll
          for (int i = 0; i < 3; ++i)
            wv[q * 3 + i] = ALPHA * (shv[1 + i] * c0acc[q] + shv[0] * c1acc[i][q]);
#pragma unroll
        for (int p = 0; p < 3; ++p) {
          f32x4 v = {wv[4 * p], wv[4 * p + 1], wv[4 * p + 2], wv[4 * p + 3]};
          TPS<T>::st4(tpr + 16 + 12 * g + 4 * p, v);
        }
      }
    }
  }
}

// ---------------- CSR build ----------------
__global__ __launch_bounds__(256) void hist_kernel(const int* __restrict__ ei,
                                                   int* __restrict__ deg) {
  for (int e = blockIdx.x * 256 + threadIdx.x; e < NE; e += gridDim.x * 256)
    atomicAdd(&deg[ei[NE + e]], 1);
}

__global__ __launch_bounds__(1024) void scan_kernel(const int* __restrict__ deg,
                                                    int* __restrict__ rowoff,
                                                    int* __restrict__ wcur) {
  __shared__ int s[1024];
  int t = threadIdx.x;
  int base = t * 10;
  int sum = 0;
#pragma unroll
  for (int j = 0; j < 10; ++j) { int n = base + j; sum += (n < NN) ? deg[n] : 0; }
  s[t] = sum;
  __syncthreads();
  for (int off = 1; off < 1024; off <<= 1) {
    int v = (t >= off) ? s[t - off] : 0;
    __syncthreads();
    s[t] += v;
    __syncthreads();
  }
  int run = s[t] - sum;
#pragma unroll
  for (int j = 0; j < 10; ++j) {
    int n = base + j;
    if (n < NN) { rowoff[n] = run; wcur[n] = run; run += deg[n]; }
  }
  if (t == 1023) rowoff[NN] = s[1023];
}

__global__ __launch_bounds__(256) void fill_kernel(const int* __restrict__ ei,
                                                   int* __restrict__ wcur,
                                                   int* __restrict__ perm) {
  for (int e = blockIdx.x * 256 + threadIdx.x; e < NE; e += gridDim.x * 256) {
    int pos = atomicAdd(&wcur[ei[NE + e]], 1);
    perm[e] = pos;
  }
}

// ---------------- gather + last-block stats reduce ----------------
template <typename T>
__global__ __launch_bounds__(256) void gather_kernel(
    const T* __restrict__ tp, const int* __restrict__ rowoff,
    const float* __restrict__ nf, float* __restrict__ pre,
    float* __restrict__ pstats, float* __restrict__ stats,
    int* __restrict__ done)
{
  __shared__ float ls[40];
  const int tid = threadIdx.x;
  if (tid < 40) ls[tid] = 0.f;
  __syncthreads();
  const int wid = tid >> 6, lane = tid & 63;
  float sacc = 0.f, qacc = 0.f;
  if (lane < 40) {
#pragma unroll 1
    for (int i = 0; i < 4; ++i) {
      const int n = blockIdx.x * 16 + wid * 4 + i;   // GBLK*16 == NN exactly
      const int r0 = rowoff[n], r1 = rowoff[n + 1];
      float s0 = 0.f, s1 = 0.f, s2 = 0.f, s3 = 0.f,
            s4 = 0.f, s5 = 0.f, s6 = 0.f, s7 = 0.f;
      int k = r0;
      for (; k + 8 <= r1; k += 8) {
        s0 += TPS<T>::ld(tp + (size_t)(k + 0) * TPSTR + lane);
        s1 += TPS<T>::ld(tp + (size_t)(k + 1) * TPSTR + lane);
        s2 += TPS<T>::ld(tp + (size_t)(k + 2) * TPSTR + lane);
        s3 += TPS<T>::ld(tp + (size_t)(k + 3) * TPSTR + lane);
        s4 += TPS<T>::ld(tp + (size_t)(k + 4) * TPSTR + lane);
        s5 += TPS<T>::ld(tp + (size_t)(k + 5) * TPSTR + lane);
        s6 += TPS<T>::ld(tp + (size_t)(k + 6) * TPSTR + lane);
        s7 += TPS<T>::ld(tp + (size_t)(k + 7) * TPSTR + lane);
      }
      for (; k < r1; ++k) s0 += TPS<T>::ld(tp + (size_t)k * TPSTR + lane);
      float s = ((s0 + s1) + (s2 + s3)) + ((s4 + s5) + (s6 + s7));
      float val = s / fmaxf((float)(r1 - r0), 1.f) + nf[(size_t)n * 40 + lane];
      pre[(size_t)n * 40 + lane] = val;
      if (lane < 16) { sacc += val; qacc += val * val; }
      else qacc += val * val;
    }
    if (lane < 16) {
      atomicAdd(&ls[lane], sacc);
      atomicAdd(&ls[16 + lane], qacc);
    } else {
      atomicAdd(&ls[32 + (lane - 16) / 3], qacc);
    }
  }
  __syncthreads();
  if (tid < 40) pstats[(size_t)blockIdx.x * 40 + tid] = ls[tid];
  __threadfence();
  __syncthreads();
  __shared__ int amlast;
  if (tid == 0) amlast = (atomicAdd(done, 1) == GBLK - 1) ? 1 : 0;
  __syncthreads();
  if (amlast) {
    __threadfence();
    __shared__ float red2[4][40];
    float s = 0.f;
    if (lane < 40) {
      for (int i = wid; i < GBLK; i += 4) s += pstats[(size_t)i * 40 + lane];
      red2[wid][lane] = s;
    }
    __syncthreads();
    if (tid < 40)
      stats[tid] = (red2[0][tid] + red2[1][tid]) + (red2[2][tid] + red2[3][tid]);
  }
}

__global__ __launch_bounds__(256) void node_pass2(
    const float* __restrict__ pre, const float* __restrict__ stats,
    const float* __restrict__ bnws, const float* __restrict__ bnbs,
    const float* __restrict__ bnwv, float* __restrict__ out)
{
  int idx = blockIdx.x * blockDim.x + threadIdx.x;
  if (idx >= NN * 40) return;
  int n = idx / 40;
  int c = idx - n * 40;
  float val = pre[idx];
  constexpr float invN = 1.0f / NN;
  if (c < 16) {
    float mu = stats[c] * invN;
    float var = stats[16 + c] * invN - mu * mu;
    out[idx] = (val - mu) * (rsqrtf(var + EPSV) * bnws[c]) + bnbs[c];
  } else {
    int u = (c - 16) / 3;
    float vn = stats[32 + u] * (invN / 3.0f);
    out[idx] = val * (rsqrtf(vn + EPSV) * bnwv[u]);
  }
}

__global__ __launch_bounds__(256) void copy_ef(const f32x4* __restrict__ src,
                                               f32x4* __restrict__ dst) {
  const int n4 = NE * 64 / 4;
  for (int i = blockIdx.x * blockDim.x + threadIdx.x; i < n4;
       i += gridDim.x * blockDim.x)
    dst[i] = src[i];
}

extern "C" void kernel_launch(void* const* d_in, const int* in_sizes, int n_in,
                              void* d_out, int out_size, void* d_ws, size_t ws_size,
                              hipStream_t stream) {
  (void)in_sizes; (void)n_in; (void)out_size;
  const float* nf   = (const float*)d_in[0];
  const float* ef   = (const float*)d_in[1];
  const float* sh   = (const float*)d_in[2];
  const int*   ei   = (const int*)d_in[3];
  const float* w1   = (const float*)d_in[4];
  const float* b1   = (const float*)d_in[5];
  const float* w2   = (const float*)d_in[6];
  const float* b2   = (const float*)d_in[7];
  const float* bnws = (const float*)d_in[8];
  const float* bnbs = (const float*)d_in[9];
  const float* bnwv = (const float*)d_in[10];

  float* out = (float*)d_out;
  float* efout = out + (size_t)NN * 40;

  // ws layout
  char* w = (char*)d_ws;
  int* deg     = (int*)w;                               // NN (zeroed by mlp1 aux)
  float* stats = (float*)(w + (size_t)NN * 4);          // 40 + pad; [47] = done
  int* done    = (int*)stats + 47;
  int* rowoff  = (int*)(w + (size_t)NN * 4 + 192);      // NN+1
  int* wcur    = rowoff + NN + 1;
  int* perm    = wcur + NN;                             // NE
  float* pre   = (float*)(perm + NE);                   // NN*40
  float* pstats = pre + (size_t)NN * 40;                // GBLK*40
  size_t base  = ((size_t)((char*)(pstats + (size_t)GBLK * 40) - w) + 255) & ~(size_t)255;
  short8* w2bf = (short8*)(w + base);                   // 73728 B
  size_t tpoff = (base + 73728 + 255) & ~(size_t)255;

  const size_t TPB_F32 = (size_t)NE * TPSTR * 4;        // 30.7 MB
  const size_t HFB     = (size_t)NT * 128 * 16;         // 20.48 MB
  const size_t needA = tpoff + TPB_F32 + HFB;
  const size_t needB = tpoff + TPB_F32;

  hipFuncSetAttribute((const void*)conv_kernel<float>,
                      hipFuncAttributeMaxDynamicSharedMemorySize, SM_AB);
  hipFuncSetAttribute((const void*)conv_kernel<ushort>,
                      hipFuncAttributeMaxDynamicSharedMemorySize, SM_AB);

  const int pblocks = (NN * 40 + 255) / 256;

  if (ws_size >= needA) {            // Plan A: everything in ws
    float* tp = (float*)(w + tpoff);
    short8* hfrag = (short8*)(w + tpoff + TPB_F32);
    mlp1_kernel<<<MLP1_GRID, 256, 0, stream>>>(ef, w1, b1, hfrag, efout, 1, w2, w2bf, deg);
    hist_kernel<<<625, 256, 0, stream>>>(ei, deg);
    scan_kernel<<<1, 1024, 0, stream>>>(deg, rowoff, wcur);
    fill_kernel<<<625, 256, 0, stream>>>(ei, wcur, perm);
    conv_kernel<float><<<GA + GB, 512, SM_AB, stream>>>(hfrag, w2bf, b2, nf, sh, ei, perm, tp);
    gather_kernel<float><<<GBLK, 256, 0, stream>>>(tp, rowoff, nf, pre, pstats, stats, done);
    node_pass2<<<pblocks, 256, 0, stream>>>(pre, stats, bnws, bnbs, bnwv, out);
  } else if (ws_size >= needB) {     // Plan B: hfrag borrows efout, copy later
    float* tp = (float*)(w + tpoff);
    short8* hfrag = (short8*)efout;
    mlp1_kernel<<<MLP1_GRID, 256, 0, stream>>>(ef, w1, b1, hfrag, efout, 0, w2, w2bf, deg);
    hist_kernel<<<625, 256, 0, stream>>>(ei, deg);
    scan_kernel<<<1, 1024, 0, stream>>>(deg, rowoff, wcur);
    fill_kernel<<<625, 256, 0, stream>>>(ei, wcur, perm);
    conv_kernel<float><<<GA + GB, 512, SM_AB, stream>>>(hfrag, w2bf, b2, nf, sh, ei, perm, tp);
    gather_kernel<float><<<GBLK, 256, 0, stream>>>(tp, rowoff, nf, pre, pstats, stats, done);
    node_pass2<<<pblocks, 256, 0, stream>>>(pre, stats, bnws, bnbs, bnwv, out);
    copy_ef<<<2048, 256, 0, stream>>>((const f32x4*)ef, (f32x4*)efout);
  } else {                           // Plan D: bf16 tp + hfrag both in efout region
    ushort* tp = (ushort*)efout;                              // 15.4 MB
    short8* hfrag = (short8*)((char*)efout + (size_t)NE * TPSTR * 2);
    mlp1_kernel<<<MLP1_GRID, 256, 0, stream>>>(ef, w1, b1, hfrag, efout, 0, w2, w2bf, deg);
    hist_kernel<<<625, 256, 0, stream>>>(ei, deg);
    scan_kernel<<<1, 1024, 0, stream>>>(deg, rowoff, wcur);
    fill_kernel<<<625, 256, 0, stream>>>(ei, wcur, perm);
    conv_kernel<ushort><<<GA + GB, 512, SM_AB, stream>>>(hfrag, w2bf, b2, nf, sh, ei, perm, tp);
    gather_kernel<ushort><<<GBLK, 256, 0, stream>>>(tp, rowoff, nf, pre, pstats, stats, done);
    node_pass2<<<pblocks, 256, 0, stream>>>(pre, stats, bnws, bnbs, bnwv, out);
    copy_ef<<<2048, 256, 0, stream>>>((const f32x4*)ef, (f32x4*)efout);
  }
}

// Round 16
// 111.437 us; speedup vs baseline: 1.6939x; 1.6939x over previous
//
#include <hip/hip_runtime.h>

typedef __attribute__((ext_vector_type(8))) short short8;
typedef __attribute__((ext_vector_type(4))) float f32x4;
typedef __attribute__((ext_vector_type(2))) float f32x2;
typedef __attribute__((ext_vector_type(4))) ushort u16x4;

constexpr int NN = 10000;
constexpr int NE = 160000;
constexpr int NT = NE / 16;                    // 10000 edge-tiles
constexpr int TPSTR = 48;                      // tp row stride (192 B = 3 lines)
constexpr int GBLK = 625;                      // gather blocks (625*16 = NN)
constexpr float EPSV = 1e-5f;
constexpr float INV3 = 0.57735026918962576f;   // 1/sqrt(3)
constexpr float ALPHA = 0.20412414523193152f;  // 1/sqrt(16+8)

__device__ __forceinline__ ushort f2bf(float x) {
  unsigned u = __float_as_uint(x);
  u += 0x7fffu + ((u >> 16) & 1u);
  return (ushort)(u >> 16);
}
__device__ __forceinline__ float bf2f(ushort u) {
  return __uint_as_float(((unsigned)u) << 16);
}
__device__ __forceinline__ f32x4 mfma16(short8 a, short8 b, f32x4 c) {
  return __builtin_amdgcn_mfma_f32_16x16x32_bf16(a, b, c, 0, 0, 0);
}

template <typename T> struct TPS;
template <> struct TPS<float> {
  static __device__ __forceinline__ void st4(float* p, f32x4 v) { *(f32x4*)p = v; }
  static __device__ __forceinline__ float ld(const float* p) { return *p; }
};
template <> struct TPS<ushort> {
  static __device__ __forceinline__ void st4(ushort* p, f32x4 v) {
    u16x4 o;
#pragma unroll
    for (int j = 0; j < 4; ++j) o[j] = f2bf(v[j]);
    *(u16x4*)p = o;
  }
  static __device__ __forceinline__ float ld(const ushort* p) { return bf2f(*p); }
};

// ---------------- K1: mlp1 + merged aux (W2 prep, deg zero) ----------------
constexpr int MLP1_MAIN = 2500;
constexpr int MLP1_GRID = MLP1_MAIN + 18 + 40;

__global__ __launch_bounds__(256) void mlp1_kernel(
    const float* __restrict__ ef, const float* __restrict__ w1,
    const float* __restrict__ b1, short8* __restrict__ hfrag,
    float* __restrict__ efout, int do_copy,
    const float* __restrict__ w2, short8* __restrict__ w2bf,
    int* __restrict__ degz)
{
  __shared__ short8 w1f[512];
  __shared__ ushort hlds[4][16 * 72];

  if (blockIdx.x >= MLP1_MAIN) {
    int aux = blockIdx.x - MLP1_MAIN;
    if (aux < 18) {                 // W2 prep: unit = 2*jt + kc, 72 units
      int unit = aux * 4 + (threadIdx.x >> 6);
      int lane = threadIdx.x & 63;
      int jt = unit >> 1, kc = unit & 1;
      int g = lane >> 4, c = lane & 15;
      short8 v;
#pragma unroll
      for (int j = 0; j < 8; ++j)
        v[j] = (short)f2bf(w2[(kc * 32 + 8 * g + j) * 576 + jt * 16 + c]);
      w2bf[(jt * 2 + kc) * 64 + lane] = v;
    } else {                        // zero deg (+stats region, harmless)
      int idx = (aux - 18) * 256 + threadIdx.x;
      if (idx < NN + 48) degz[idx] = 0;
    }
    return;
  }

  for (int t = threadIdx.x; t < 512; t += 256) {
    int tile = t >> 6, l = t & 63;
    int nt = tile >> 1, kc = tile & 1;
    int gg = l >> 4, cc = l & 15;
    short8 v;
#pragma unroll
    for (int j = 0; j < 8; ++j)
      v[j] = (short)f2bf(w1[(kc * 32 + 8 * gg + j) * 64 + nt * 16 + cc]);
    w1f[t] = v;
  }
  __syncthreads();

  const int lane = threadIdx.x & 63, wid = threadIdx.x >> 6;
  const int g = lane >> 4, c = lane & 15;
  const long tile = (long)blockIdx.x * 4 + wid;
  const long ebase = tile * 16;

  short8 af[2];
  const float* rowp = ef + (ebase + c) * 64;
#pragma unroll
  for (int kc = 0; kc < 2; ++kc) {
    const f32x4* p = (const f32x4*)(rowp + kc * 32 + 8 * g);
    f32x4 lo = p[0], hi = p[1];
    if (do_copy) {
      f32x4* q = (f32x4*)(efout + (ebase + c) * 64 + kc * 32 + 8 * g);
      q[0] = lo; q[1] = hi;
    }
    short8 v;
#pragma unroll
    for (int j = 0; j < 4; ++j) { v[j] = (short)f2bf(lo[j]); v[4 + j] = (short)f2bf(hi[j]); }
    af[kc] = v;
  }

  f32x4 acc[4] = {};
#pragma unroll
  for (int nt = 0; nt < 4; ++nt)
#pragma unroll
    for (int kc = 0; kc < 2; ++kc)
      acc[nt] = mfma16(af[kc], w1f[(nt * 2 + kc) * 64 + lane], acc[nt]);

#pragma unroll
  for (int nt = 0; nt < 4; ++nt) {
    float bv = b1[nt * 16 + c];
#pragma unroll
    for (int q = 0; q < 4; ++q) {
      float h = fmaxf(acc[nt][q] + bv, 0.f);
      hlds[wid][(4 * g + q) * 72 + nt * 16 + c] = f2bf(h);
    }
  }
#pragma unroll
  for (int kc = 0; kc < 2; ++kc) {
    short8 hv = *(const short8*)&hlds[wid][c * 72 + kc * 32 + 8 * g];
    hfrag[(tile * 2 + kc) * 64 + lane] = hv;
  }
}

// ---------------- K2: split conv -- role A (out0) / role B (out1) ----------------
constexpr int GA = 320, GB = 192;              // grid split (LDS-cycle balanced)
constexpr int CSTRA = 28;                      // a0[16] + a1[8] + pad
constexpr int CSTRB = 44;                      // x0[16] + x1[24] + pad
constexpr unsigned SMA_W2 = 3072 * 16;         // 49152 B (jt 0..23)
constexpr unsigned SMA_B2 = 384 * 4;
constexpr unsigned SMA_SCR = 8 * 16 * CSTRA * 4;   // 14336 B
constexpr unsigned SM_AB = SMA_W2 + SMA_B2 + SMA_SCR;  // 65024 B (role max)
constexpr unsigned SMB_W2 = 1536 * 16;         // 24576 B (jt 24..35)
constexpr unsigned SMB_B2 = 192 * 4;

template <typename T>
__global__ __launch_bounds__(512) void conv_kernel(
    const short8* __restrict__ hfrag, const short8* __restrict__ w2bf,
    const float* __restrict__ b2, const float* __restrict__ nf,
    const float* __restrict__ sh, const int* __restrict__ ei,
    const int* __restrict__ perm, T* __restrict__ tp)
{
  extern __shared__ char smem[];
  const int tid = threadIdx.x;
  const int lane = tid & 63, wid = tid >> 6;
  const int g = lane >> 4, c = lane & 15;
  const int gh = g >> 1;
  const int e = lane >> 2, part = lane & 3;

  if (blockIdx.x < GA) {
    // role A: out0
    short8* w2l = (short8*)smem;
    float* b2l = (float*)(smem + SMA_W2);
    float* scrall = (float*)(smem + SMA_W2 + SMA_B2);
    for (int i = tid; i < 3072; i += 512) w2l[i] = w2bf[i];
    for (int i = tid; i < 384; i += 512) b2l[i] = b2[i];
    __syncthreads();
    float* scr = scrall + wid * (16 * CSTRA);

    for (int t = blockIdx.x * 8 + wid; t < NT; t += GA * 8) {
      {
        const int ege = t * 16 + e;
        const float* __restrict__ src = nf + (size_t)ei[ege] * 40;
        const f32x4 sv = *(const f32x4*)(sh + (size_t)ege * 4);
        float* ce = scr + e * CSTRA;
        f32x4 v0 = *(const f32x4*)(src + part * 4);
        f32x4 a0;
#pragma unroll
        for (int q = 0; q < 4; ++q) a0[q] = sv[0] * v0[q];
        *(f32x4*)(ce + 4 * part) = a0;
        const f32x2 q0 = *(const f32x2*)(src + 16 + 6 * part);
        const f32x2 q1 = *(const f32x2*)(src + 18 + 6 * part);
        const f32x2 q2 = *(const f32x2*)(src + 20 + 6 * part);
        ce[16 + 2 * part]     = INV3 * (q0.x * sv[1] + q0.y * sv[2] + q1.x * sv[3]);
        ce[16 + 2 * part + 1] = INV3 * (q1.y * sv[1] + q2.x * sv[2] + q2.y * sv[3]);
      }
      const short8 h0 = hfrag[(size_t)(t * 2 + 0) * 64 + lane];
      const short8 h1 = hfrag[(size_t)(t * 2 + 1) * 64 + lane];
      const float* __restrict__ cc = scr + c * CSTRA;
      f32x4 acc = {0.f, 0.f, 0.f, 0.f};
#pragma unroll
      for (int jt = 0; jt < 24; ++jt) {
        f32x4 d = *(const f32x4*)&b2l[jt * 16 + 4 * g];
        d = mfma16(w2l[(jt * 2 + 0) * 64 + lane], h0, d);
        d = mfma16(w2l[(jt * 2 + 1) * 64 + lane], h1, d);
        float a = cc[jt];
#pragma unroll
        for (int q = 0; q < 4; ++q) acc[q] = fmaf(a, d[q], acc[q]);
      }
      const int eg = t * 16 + c;
      T* tpr = tp + (size_t)perm[eg] * TPSTR;
      f32x4 o0;
#pragma unroll
      for (int q = 0; q < 4; ++q) o0[q] = ALPHA * acc[q];
      TPS<T>::st4(tpr + 4 * g, o0);
    }
  } else {
    // role B: out1
    short8* w2l = (short8*)smem;
    float* b2l = (float*)(smem + SMB_W2);
    float* scrall = (float*)(smem + SMB_W2 + SMB_B2);
    for (int i = tid; i < 1536; i += 512) w2l[i] = w2bf[3072 + i];
    for (int i = tid; i < 192; i += 512) b2l[i] = b2[384 + i];
    __syncthreads();
    float* scr = scrall + wid * (16 * CSTRB);

    for (int t = (blockIdx.x - GA) * 8 + wid; t < NT; t += GB * 8) {
      {
        const int ege = t * 16 + e;
        const float* __restrict__ src = nf + (size_t)ei[ege] * 40;
        float* ce = scr + e * CSTRB;
        *(f32x4*)(ce + 4 * part)      = *(const f32x4*)(src + part * 4);
        *(f32x4*)(ce + 16 + 4 * part) = *(const f32x4*)(src + 16 + part * 4);
        if (part < 2)
          *(f32x4*)(ce + 32 + 4 * part) = *(const f32x4*)(src + 32 + part * 4);
      }
      const short8 h0 = hfrag[(size_t)(t * 2 + 0) * 64 + lane];
      const short8 h1 = hfrag[(size_t)(t * 2 + 1) * 64 + lane];
      const float* __restrict__ cc = scr + c * CSTRB;
      f32x4 c0acc = {0.f, 0.f, 0.f, 0.f};
      f32x4 c1acc[3] = {};
#pragma unroll
      for (int j2 = 0; j2 < 8; ++j2) {       // w01: u = 2*j2+gh
        f32x4 d = *(const f32x4*)&b2l[j2 * 16 + 4 * g];
        d = mfma16(w2l[(j2 * 2 + 0) * 64 + lane], h0, d);
        d = mfma16(w2l[(j2 * 2 + 1) * 64 + lane], h1, d);
        float a = cc[2 * j2 + gh];
#pragma unroll
        for (int q = 0; q < 4; ++q) c0acc[q] = fmaf(a, d[q], c0acc[q]);
      }
#pragma unroll
      for (int j2 = 8; j2 < 12; ++j2) {      // w10: u = 2*(j2-8)+gh
        f32x4 d = *(const f32x4*)&b2l[j2 * 16 + 4 * g];
        d = mfma16(w2l[(j2 * 2 + 0) * 64 + lane], h0, d);
        d = mfma16(w2l[(j2 * 2 + 1) * 64 + lane], h1, d);
        const int ub = 16 + 3 * (2 * (j2 - 8) + gh);
#pragma unroll
        for (int i = 0; i < 3; ++i) {
          float a = cc[ub + i];
#pragma unroll
          for (int q = 0; q < 4; ++q) c1acc[i][q] = fmaf(a, d[q], c1acc[i][q]);
        }
      }
#pragma unroll
      for (int q = 0; q < 4; ++q) c0acc[q] += __shfl_xor(c0acc[q], 32);
#pragma unroll
      for (int i = 0; i < 3; ++i)
#pragma unroll
        for (int q = 0; q < 4; ++q) c1acc[i][q] += __shfl_xor(c1acc[i][q], 32);

      const int eg = t * 16 + c;
      const f32x4 shv = *(const f32x4*)(sh + (size_t)eg * 4);
      T* tpr = tp + (size_t)perm[eg] * TPSTR;
      if (g < 2) {
        float wv[12];
#pragma unroll
        for (int q = 0; q < 4; ++q)
#pragma unroll
          for (int i = 0; i < 3; ++i)
            wv[q * 3 + i] = ALPHA * (shv[1 + i] * c0acc[q] + shv[0] * c1acc[i][q]);
#pragma unroll
        for (int p = 0; p < 3; ++p) {
          f32x4 v = {wv[4 * p], wv[4 * p + 1], wv[4 * p + 2], wv[4 * p + 3]};
          TPS<T>::st4(tpr + 16 + 12 * g + 4 * p, v);
        }
      }
    }
  }
}

// ---------------- CSR build ----------------
__global__ __launch_bounds__(256) void hist_kernel(const int* __restrict__ ei,
                                                   int* __restrict__ deg) {
  for (int e = blockIdx.x * 256 + threadIdx.x; e < NE; e += gridDim.x * 256)
    atomicAdd(&deg[ei[NE + e]], 1);
}

__global__ __launch_bounds__(1024) void scan_kernel(const int* __restrict__ deg,
                                                    int* __restrict__ rowoff,
                                                    int* __restrict__ wcur) {
  __shared__ int s[1024];
  int t = threadIdx.x;
  int base = t * 10;
  int sum = 0;
#pragma unroll
  for (int j = 0; j < 10; ++j) { int n = base + j; sum += (n < NN) ? deg[n] : 0; }
  s[t] = sum;
  __syncthreads();
  for (int off = 1; off < 1024; off <<= 1) {
    int v = (t >= off) ? s[t - off] : 0;
    __syncthreads();
    s[t] += v;
    __syncthreads();
  }
  int run = s[t] - sum;
#pragma unroll
  for (int j = 0; j < 10; ++j) {
    int n = base + j;
    if (n < NN) { rowoff[n] = run; wcur[n] = run; run += deg[n]; }
  }
  if (t == 1023) rowoff[NN] = s[1023];
}

__global__ __launch_bounds__(256) void fill_kernel(const int* __restrict__ ei,
                                                   int* __restrict__ wcur,
                                                   int* __restrict__ perm) {
  for (int e = blockIdx.x * 256 + threadIdx.x; e < NE; e += gridDim.x * 256) {
    int pos = atomicAdd(&wcur[ei[NE + e]], 1);
    perm[e] = pos;
  }
}

// ---------------- gather: linear CSR rows; per-block pstats (NON-atomic) ----------------
// r15 post-mortem: fused last-block reduce with per-block __threadfence()
// cost 96 us (device fence = L2 writeback x625 blocks). Cross-block
// reduction goes in a separate kernel (implicit device sync at boundary).
template <typename T>
__global__ __launch_bounds__(256) void gather_kernel(
    const T* __restrict__ tp, const int* __restrict__ rowoff,
    const float* __restrict__ nf, float* __restrict__ pre,
    float* __restrict__ pstats)
{
  __shared__ float ls[40];
  const int tid = threadIdx.x;
  if (tid < 40) ls[tid] = 0.f;
  __syncthreads();
  const int wid = tid >> 6, lane = tid & 63;
  float sacc = 0.f, qacc = 0.f;
  if (lane < 40) {
#pragma unroll 1
    for (int i = 0; i < 4; ++i) {
      const int n = blockIdx.x * 16 + wid * 4 + i;   // GBLK*16 == NN exactly
      const int r0 = rowoff[n], r1 = rowoff[n + 1];
      float s0 = 0.f, s1 = 0.f, s2 = 0.f, s3 = 0.f,
            s4 = 0.f, s5 = 0.f, s6 = 0.f, s7 = 0.f;
      int k = r0;
      for (; k + 8 <= r1; k += 8) {
        s0 += TPS<T>::ld(tp + (size_t)(k + 0) * TPSTR + lane);
        s1 += TPS<T>::ld(tp + (size_t)(k + 1) * TPSTR + lane);
        s2 += TPS<T>::ld(tp + (size_t)(k + 2) * TPSTR + lane);
        s3 += TPS<T>::ld(tp + (size_t)(k + 3) * TPSTR + lane);
        s4 += TPS<T>::ld(tp + (size_t)(k + 4) * TPSTR + lane);
        s5 += TPS<T>::ld(tp + (size_t)(k + 5) * TPSTR + lane);
        s6 += TPS<T>::ld(tp + (size_t)(k + 6) * TPSTR + lane);
        s7 += TPS<T>::ld(tp + (size_t)(k + 7) * TPSTR + lane);
      }
      for (; k < r1; ++k) s0 += TPS<T>::ld(tp + (size_t)k * TPSTR + lane);
      float s = ((s0 + s1) + (s2 + s3)) + ((s4 + s5) + (s6 + s7));
      float val = s / fmaxf((float)(r1 - r0), 1.f) + nf[(size_t)n * 40 + lane];
      pre[(size_t)n * 40 + lane] = val;
      if (lane < 16) { sacc += val; qacc += val * val; }
      else qacc += val * val;
    }
    if (lane < 16) {
      atomicAdd(&ls[lane], sacc);
      atomicAdd(&ls[16 + lane], qacc);
    } else {
      atomicAdd(&ls[32 + (lane - 16) / 3], qacc);
    }
  }
  __syncthreads();
  if (tid < 40) pstats[(size_t)blockIdx.x * 40 + tid] = ls[tid];
}

// 40 blocks: channel c = blockIdx; sum 625 block-partials
__global__ __launch_bounds__(256) void stats_reduce(
    const float* __restrict__ pstats, float* __restrict__ stats)
{
  const int c = blockIdx.x;
  float s = 0.f;
  for (int i = threadIdx.x; i < GBLK; i += 256) s += pstats[(size_t)i * 40 + c];
#pragma unroll
  for (int off = 1; off < 64; off <<= 1) s += __shfl_xor(s, off);
  __shared__ float red[4];
  if ((threadIdx.x & 63) == 0) red[threadIdx.x >> 6] = s;
  __syncthreads();
  if (threadIdx.x == 0) stats[c] = (red[0] + red[1]) + (red[2] + red[3]);
}

__global__ __launch_bounds__(256) void node_pass2(
    const float* __restrict__ pre, const float* __restrict__ stats,
    const float* __restrict__ bnws, const float* __restrict__ bnbs,
    const float* __restrict__ bnwv, float* __restrict__ out)
{
  int idx = blockIdx.x * blockDim.x + threadIdx.x;
  if (idx >= NN * 40) return;
  int n = idx / 40;
  int c = idx - n * 40;
  float val = pre[idx];
  constexpr float invN = 1.0f / NN;
  if (c < 16) {
    float mu = stats[c] * invN;
    float var = stats[16 + c] * invN - mu * mu;
    out[idx] = (val - mu) * (rsqrtf(var + EPSV) * bnws[c]) + bnbs[c];
  } else {
    int u = (c - 16) / 3;
    float vn = stats[32 + u] * (invN / 3.0f);
    out[idx] = val * (rsqrtf(vn + EPSV) * bnwv[u]);
  }
}

__global__ __launch_bounds__(256) void copy_ef(const f32x4* __restrict__ src,
                                               f32x4* __restrict__ dst) {
  const int n4 = NE * 64 / 4;
  for (int i = blockIdx.x * blockDim.x + threadIdx.x; i < n4;
       i += gridDim.x * blockDim.x)
    dst[i] = src[i];
}

extern "C" void kernel_launch(void* const* d_in, const int* in_sizes, int n_in,
                              void* d_out, int out_size, void* d_ws, size_t ws_size,
                              hipStream_t stream) {
  (void)in_sizes; (void)n_in; (void)out_size;
  const float* nf   = (const float*)d_in[0];
  const float* ef   = (const float*)d_in[1];
  const float* sh   = (const float*)d_in[2];
  const int*   ei   = (const int*)d_in[3];
  const float* w1   = (const float*)d_in[4];
  const float* b1   = (const float*)d_in[5];
  const float* w2   = (const float*)d_in[6];
  const float* b2   = (const float*)d_in[7];
  const float* bnws = (const float*)d_in[8];
  const float* bnbs = (const float*)d_in[9];
  const float* bnwv = (const float*)d_in[10];

  float* out = (float*)d_out;
  float* efout = out + (size_t)NN * 40;

  // ws layout
  char* w = (char*)d_ws;
  int* deg     = (int*)w;                               // NN (zeroed by mlp1 aux)
  float* stats = (float*)(w + (size_t)NN * 4);          // 48 (written non-atomically)
  int* rowoff  = (int*)(w + (size_t)NN * 4 + 192);      // NN+1
  int* wcur    = rowoff + NN + 1;
  int* perm    = wcur + NN;                             // NE
  float* pre   = (float*)(perm + NE);                   // NN*40
  float* pstats = pre + (size_t)NN * 40;                // GBLK*40
  size_t base  = ((size_t)((char*)(pstats + (size_t)GBLK * 40) - w) + 255) & ~(size_t)255;
  short8* w2bf = (short8*)(w + base);                   // 73728 B
  size_t tpoff = (base + 73728 + 255) & ~(size_t)255;

  const size_t TPB_F32 = (size_t)NE * TPSTR * 4;        // 30.7 MB
  const size_t HFB     = (size_t)NT * 128 * 16;         // 20.48 MB
  const size_t needA = tpoff + TPB_F32 + HFB;
  const size_t needB = tpoff + TPB_F32;

  hipFuncSetAttribute((const void*)conv_kernel<float>,
                      hipFuncAttributeMaxDynamicSharedMemorySize, SM_AB);
  hipFuncSetAttribute((const void*)conv_kernel<ushort>,
                      hipFuncAttributeMaxDynamicSharedMemorySize, SM_AB);

  const int pblocks = (NN * 40 + 255) / 256;

  if (ws_size >= needA) {            // Plan A: everything in ws
    float* tp = (float*)(w + tpoff);
    short8* hfrag = (short8*)(w + tpoff + TPB_F32);
    mlp1_kernel<<<MLP1_GRID, 256, 0, stream>>>(ef, w1, b1, hfrag, efout, 1, w2, w2bf, deg);
    hist_kernel<<<625, 256, 0, stream>>>(ei, deg);
    scan_kernel<<<1, 1024, 0, stream>>>(deg, rowoff, wcur);
    fill_kernel<<<625, 256, 0, stream>>>(ei, wcur, perm);
    conv_kernel<float><<<GA + GB, 512, SM_AB, stream>>>(hfrag, w2bf, b2, nf, sh, ei, perm, tp);
    gather_kernel<float><<<GBLK, 256, 0, stream>>>(tp, rowoff, nf, pre, pstats);
    stats_reduce<<<40, 256, 0, stream>>>(pstats, stats);
    node_pass2<<<pblocks, 256, 0, stream>>>(pre, stats, bnws, bnbs, bnwv, out);
  } else if (ws_size >= needB) {     // Plan B: hfrag borrows efout, copy later
    float* tp = (float*)(w + tpoff);
    short8* hfrag = (short8*)efout;
    mlp1_kernel<<<MLP1_GRID, 256, 0, stream>>>(ef, w1, b1, hfrag, efout, 0, w2, w2bf, deg);
    hist_kernel<<<625, 256, 0, stream>>>(ei, deg);
    scan_kernel<<<1, 1024, 0, stream>>>(deg, rowoff, wcur);
    fill_kernel<<<625, 256, 0, stream>>>(ei, wcur, perm);
    conv_kernel<float><<<GA + GB, 512, SM_AB, stream>>>(hfrag, w2bf, b2, nf, sh, ei, perm, tp);
    gather_kernel<float><<<GBLK, 256, 0, stream>>>(tp, rowoff, nf, pre, pstats);
    stats_reduce<<<40, 256, 0, stream>>>(pstats, stats);
    node_pass2<<<pblocks, 256, 0, stream>>>(pre, stats, bnws, bnbs, bnwv, out);
    copy_ef<<<2048, 256, 0, stream>>>((const f32x4*)ef, (f32x4*)efout);
  } else {                           // Plan D: bf16 tp + hfrag both in efout region
    ushort* tp = (ushort*)efout;                              // 15.4 MB
    short8* hfrag = (short8*)((char*)efout + (size_t)NE * TPSTR * 2);
    mlp1_kernel<<<MLP1_GRID, 256, 0, stream>>>(ef, w1, b1, hfrag, efout, 0, w2, w2bf, deg);
    hist_kernel<<<625, 256, 0, stream>>>(ei, deg);
    scan_kernel<<<1, 1024, 0, stream>>>(deg, rowoff, wcur);
    fill_kernel<<<625, 256, 0, stream>>>(ei, wcur, perm);
    conv_kernel<ushort><<<GA + GB, 512, SM_AB, stream>>>(hfrag, w2bf, b2, nf, sh, ei, perm, tp);
    gather_kernel<ushort><<<GBLK, 256, 0, stream>>>(tp, rowoff, nf, pre, pstats);
    stats_reduce<<<40, 256, 0, stream>>>(pstats, stats);
    node_pass2<<<pblocks, 256, 0, stream>>>(pre, stats, bnws, bnbs, bnwv, out);
    copy_ef<<<2048, 256, 0, stream>>>((const f32x4*)ef, (f32x4*)efout);
  }
}

// Round 17
// 104.009 us; speedup vs baseline: 1.8149x; 1.0714x over previous
//
#include <hip/hip_runtime.h>

typedef __attribute__((ext_vector_type(8))) short short8;
typedef __attribute__((ext_vector_type(4))) float f32x4;
typedef __attribute__((ext_vector_type(4))) ushort u16x4;

constexpr int NN = 10000;
constexpr int NE = 160000;
constexpr int NT = NE / 16;                    // 10000 edge-tiles
constexpr int TPSTR = 48;                      // tp row stride (192 B = 3 lines)
constexpr int GBLK = 625;                      // gather blocks (625*16 = NN)
constexpr float EPSV = 1e-5f;
constexpr float INV3 = 0.57735026918962576f;   // 1/sqrt(3)
constexpr float ALPHA = 0.20412414523193152f;  // 1/sqrt(16+8)

__device__ __forceinline__ ushort f2bf(float x) {
  unsigned u = __float_as_uint(x);
  u += 0x7fffu + ((u >> 16) & 1u);
  return (ushort)(u >> 16);
}
__device__ __forceinline__ float bf2f(ushort u) {
  return __uint_as_float(((unsigned)u) << 16);
}
__device__ __forceinline__ f32x4 mfma16(short8 a, short8 b, f32x4 c) {
  return __builtin_amdgcn_mfma_f32_16x16x32_bf16(a, b, c, 0, 0, 0);
}

template <typename T> struct TPS;
template <> struct TPS<float> {
  static __device__ __forceinline__ void st4(float* p, f32x4 v) { *(f32x4*)p = v; }
  static __device__ __forceinline__ float ld(const float* p) { return *p; }
};
template <> struct TPS<ushort> {
  static __device__ __forceinline__ void st4(ushort* p, f32x4 v) {
    u16x4 o;
#pragma unroll
    for (int j = 0; j < 4; ++j) o[j] = f2bf(v[j]);
    *(u16x4*)p = o;
  }
  static __device__ __forceinline__ float ld(const ushort* p) { return bf2f(*p); }
};

// ---------------- K0: W2 -> bf16 A-frag layout; blocks >=72 zero deg ----------------
__global__ __launch_bounds__(64) void prep_w2(const float* __restrict__ w2,
                                              short8* __restrict__ w2bf,
                                              int* __restrict__ deg) {
  int b = blockIdx.x;
  int lane = threadIdx.x;
  if (b < 72) {                // 72 = 36 jt * 2 kc
    int jt = b >> 1, kc = b & 1;
    int g = lane >> 4, c = lane & 15;
    short8 v;
#pragma unroll
    for (int j = 0; j < 8; ++j)
      v[j] = (short)f2bf(w2[(kc * 32 + 8 * g + j) * 576 + jt * 16 + c]);
    w2bf[(jt * 2 + kc) * 64 + lane] = v;
  } else {
    int idx = (b - 72) * 64 + lane;
    if (idx < NN) deg[idx] = 0;
  }
}

// ---------------- K2: FUSED mlp1+conv -- per-wave 16-edge tile ----------------
// r16 post-mortem: A/B occupancy split was neutral (conv is latency-bound,
// pipes idle) -> absorb mlp1's work into conv's idle slots instead:
//   phase 0: issue ei->nf/sh gather loads (latency hides under phases 1-2)
//   phase 1: ef loads (+copy-out) + 8 MFMA  (mlp1 GEMM, W1 frags in LDS)
//   phase 2: bias/relu + per-wave LDS transpose -> h0/h1 regs (r2-verified)
//   phase 3: coef table from phase-0 regs (r14 staging)
//   phase 4: unified r14 jt loops + fold + CSR store
// Eliminates the hfrag 20MB write + 40MB read and the separate mlp1 launch.
constexpr int CSTR = 68;
constexpr unsigned SM_W2 = 4608 * 16;                       // 73728 B
constexpr unsigned SM_B2 = 576 * 4;                         // 2304 B
constexpr unsigned SM_W1 = 512 * 16;                        // 8192 B
constexpr unsigned SM_B1 = 64 * 4;                          // 256 B
constexpr unsigned SM_HL = 8 * 16 * 72 * 2;                 // 18432 B (transpose)
constexpr unsigned SM_SCR = 8 * 16 * CSTR * 4;              // 34816 B
constexpr unsigned SM_TOTAL = SM_W2 + SM_B2 + SM_W1 + SM_B1 + SM_HL + SM_SCR; // 137728

template <typename T>
__global__ __launch_bounds__(512) void conv_kernel(
    const float* __restrict__ ef, const float* __restrict__ w1,
    const float* __restrict__ b1, const short8* __restrict__ w2bf,
    const float* __restrict__ b2, const float* __restrict__ nf,
    const float* __restrict__ sh, const int* __restrict__ ei,
    const int* __restrict__ perm, float* __restrict__ efout, int do_copy,
    T* __restrict__ tp)
{
  extern __shared__ char smem[];
  short8* w2lds = (short8*)smem;
  float*  b2lds = (float*)(smem + SM_W2);
  short8* w1f   = (short8*)(smem + SM_W2 + SM_B2);
  float*  b1lds = (float*)(smem + SM_W2 + SM_B2 + SM_W1);
  ushort* hlall = (ushort*)(smem + SM_W2 + SM_B2 + SM_W1 + SM_B1);
  float*  scrall = (float*)(smem + SM_W2 + SM_B2 + SM_W1 + SM_B1 + SM_HL);

  const int tid = threadIdx.x;
  for (int i = tid; i < 4608; i += 512) w2lds[i] = w2bf[i];
  for (int i = tid; i < 576; i += 512) b2lds[i] = b2[i];
  {  // W1 -> bf16 B-frags, one per thread (512 frags)
    int tile = tid >> 6, l = tid & 63;
    int nt = tile >> 1, kc = tile & 1;
    int gg = l >> 4, cc = l & 15;
    short8 v;
#pragma unroll
    for (int j = 0; j < 8; ++j)
      v[j] = (short)f2bf(w1[(kc * 32 + 8 * gg + j) * 64 + nt * 16 + cc]);
    w1f[tid] = v;
  }
  if (tid < 64) b1lds[tid] = b1[tid];
  __syncthreads();

  const int lane = tid & 63, wid = tid >> 6;
  const int g = lane >> 4, c = lane & 15;
  const int gh = g >> 1;
  const int e = lane >> 2, part = lane & 3;
  float* scr = scrall + wid * (16 * CSTR);
  ushort* hl = hlall + wid * (16 * 72);

  for (int t = blockIdx.x * 8 + wid; t < NT; t += gridDim.x * 8) {
    // ---- phase 0: issue gather loads early (latency hides under MLP1)
    const int ege = t * 16 + e;
    const float* __restrict__ src = nf + (size_t)ei[ege] * 40;
    const f32x4 sv = *(const f32x4*)(sh + (size_t)ege * 4);
    const f32x4 v0 = *(const f32x4*)(src + part * 4);
    const f32x4 v1 = *(const f32x4*)(src + 16 + part * 4);
    f32x4 v2 = {};
    if (part < 2) v2 = *(const f32x4*)(src + 32 + part * 4);

    // ---- phase 1: MLP1 GEMM (lane c = edge of this tile)
    const long ebase = (long)t * 16;
    short8 af[2];
    const float* rowp = ef + (ebase + c) * 64;
#pragma unroll
    for (int kc = 0; kc < 2; ++kc) {
      const f32x4* p = (const f32x4*)(rowp + kc * 32 + 8 * g);
      f32x4 lo = p[0], hi = p[1];
      if (do_copy) {
        f32x4* q = (f32x4*)(efout + (ebase + c) * 64 + kc * 32 + 8 * g);
        q[0] = lo; q[1] = hi;
      }
      short8 v;
#pragma unroll
      for (int j = 0; j < 4; ++j) { v[j] = (short)f2bf(lo[j]); v[4 + j] = (short)f2bf(hi[j]); }
      af[kc] = v;
    }
    f32x4 hacc[4] = {};
#pragma unroll
    for (int nt = 0; nt < 4; ++nt)
#pragma unroll
      for (int kc = 0; kc < 2; ++kc)
        hacc[nt] = mfma16(af[kc], w1f[(nt * 2 + kc) * 64 + lane], hacc[nt]);

    // ---- phase 2: bias+relu, per-wave LDS transpose -> h0/h1 (in-wave ordered)
#pragma unroll
    for (int nt = 0; nt < 4; ++nt) {
      float bv = b1lds[nt * 16 + c];
#pragma unroll
      for (int q = 0; q < 4; ++q) {
        float h = fmaxf(hacc[nt][q] + bv, 0.f);
        hl[(4 * g + q) * 72 + nt * 16 + c] = f2bf(h);
      }
    }
    const short8 h0 = *(const short8*)&hl[c * 72 + 8 * g];
    const short8 h1 = *(const short8*)&hl[c * 72 + 32 + 8 * g];

    // ---- phase 3: coefficient table from phase-0 regs (4 lanes per edge)
    {
      float* ce = scr + e * CSTR;
      f32x4 a0;
#pragma unroll
      for (int q = 0; q < 4; ++q) a0[q] = sv[0] * v0[q];
      *(f32x4*)(ce + 4 * part) = a0;
      *(f32x4*)(ce + 24 + 4 * part) = v0;
      *(f32x4*)(ce + 40 + 4 * part) = v1;
      if (part < 2) *(f32x4*)(ce + 56 + 4 * part) = v2;
#pragma unroll
      for (int uu = 0; uu < 2; ++uu) {
        int u = 2 * part + uu;
        ce[16 + u] = INV3 * (ce[40 + 3 * u] * sv[1] + ce[41 + 3 * u] * sv[2] +
                             ce[42 + 3 * u] * sv[3]);
      }
    }
    const float* __restrict__ cc = scr + c * CSTR;

    // ---- phase 4: j-GEMM + lane-local tensor product (r14 body)
    f32x4 out0acc = {0.f, 0.f, 0.f, 0.f};
    f32x4 c0acc = {0.f, 0.f, 0.f, 0.f};
    f32x4 c1acc[3] = {};

#pragma unroll
    for (int jt = 0; jt < 16; ++jt) {          // w00: u=jt
      f32x4 d = *(const f32x4*)&b2lds[jt * 16 + 4 * g];
      d = mfma16(w2lds[(jt * 2 + 0) * 64 + lane], h0, d);
      d = mfma16(w2lds[(jt * 2 + 1) * 64 + lane], h1, d);
      float a = cc[jt];
#pragma unroll
      for (int q = 0; q < 4; ++q) out0acc[q] = fmaf(a, d[q], out0acc[q]);
    }
#pragma unroll
    for (int jt = 16; jt < 24; ++jt) {         // w11: u=jt-16
      f32x4 d = *(const f32x4*)&b2lds[jt * 16 + 4 * g];
      d = mfma16(w2lds[(jt * 2 + 0) * 64 + lane], h0, d);
      d = mfma16(w2lds[(jt * 2 + 1) * 64 + lane], h1, d);
      float a = cc[16 + (jt - 16)];
#pragma unroll
      for (int q = 0; q < 4; ++q) out0acc[q] = fmaf(a, d[q], out0acc[q]);
    }
#pragma unroll
    for (int jt = 24; jt < 32; ++jt) {         // w01: u=2(jt-24)+gh
      f32x4 d = *(const f32x4*)&b2lds[jt * 16 + 4 * g];
      d = mfma16(w2lds[(jt * 2 + 0) * 64 + lane], h0, d);
      d = mfma16(w2lds[(jt * 2 + 1) * 64 + lane], h1, d);
      float a = cc[24 + 2 * (jt - 24) + gh];
#pragma unroll
      for (int q = 0; q < 4; ++q) c0acc[q] = fmaf(a, d[q], c0acc[q]);
    }
#pragma unroll
    for (int jt = 32; jt < 36; ++jt) {         // w10: u=2(jt-32)+gh
      f32x4 d = *(const f32x4*)&b2lds[jt * 16 + 4 * g];
      d = mfma16(w2lds[(jt * 2 + 0) * 64 + lane], h0, d);
      d = mfma16(w2lds[(jt * 2 + 1) * 64 + lane], h1, d);
      const int ub = 40 + 3 * (2 * (jt - 32) + gh);
#pragma unroll
      for (int i = 0; i < 3; ++i) {
        float a = cc[ub + i];
#pragma unroll
        for (int q = 0; q < 4; ++q) c1acc[i][q] = fmaf(a, d[q], c1acc[i][q]);
      }
    }

    // fold gh halves (lane ^ 32)
#pragma unroll
    for (int q = 0; q < 4; ++q) c0acc[q] += __shfl_xor(c0acc[q], 32);
#pragma unroll
    for (int i = 0; i < 3; ++i)
#pragma unroll
      for (int q = 0; q < 4; ++q) c1acc[i][q] += __shfl_xor(c1acc[i][q], 32);

    // store into this edge's CSR slot (scattered rows, line-aligned 192 B)
    const int eg = t * 16 + c;
    const f32x4 shv = *(const f32x4*)(sh + (size_t)eg * 4);
    T* tpr = tp + (size_t)perm[eg] * TPSTR;
    f32x4 o0;
#pragma unroll
    for (int q = 0; q < 4; ++q) o0[q] = ALPHA * out0acc[q];
    TPS<T>::st4(tpr + 4 * g, o0);
    if (g < 2) {
      float wv[12];
#pragma unroll
      for (int q = 0; q < 4; ++q)
#pragma unroll
        for (int i = 0; i < 3; ++i)
          wv[q * 3 + i] = ALPHA * (shv[1 + i] * c0acc[q] + shv[0] * c1acc[i][q]);
#pragma unroll
      for (int p = 0; p < 3; ++p) {
        f32x4 v = {wv[4 * p], wv[4 * p + 1], wv[4 * p + 2], wv[4 * p + 3]};
        TPS<T>::st4(tpr + 16 + 12 * g + 4 * p, v);
      }
    }
  }
}

// ---------------- CSR build ----------------
__global__ __launch_bounds__(256) void hist_kernel(const int* __restrict__ ei,
                                                   int* __restrict__ deg) {
  for (int e = blockIdx.x * 256 + threadIdx.x; e < NE; e += gridDim.x * 256)
    atomicAdd(&deg[ei[NE + e]], 1);
}

__global__ __launch_bounds__(1024) void scan_kernel(const int* __restrict__ deg,
                                                    int* __restrict__ rowoff,
                                                    int* __restrict__ wcur) {
  __shared__ int s[1024];
  int t = threadIdx.x;
  int base = t * 10;
  int sum = 0;
#pragma unroll
  for (int j = 0; j < 10; ++j) { int n = base + j; sum += (n < NN) ? deg[n] : 0; }
  s[t] = sum;
  __syncthreads();
  for (int off = 1; off < 1024; off <<= 1) {
    int v = (t >= off) ? s[t - off] : 0;
    __syncthreads();
    s[t] += v;
    __syncthreads();
  }
  int run = s[t] - sum;
#pragma unroll
  for (int j = 0; j < 10; ++j) {
    int n = base + j;
    if (n < NN) { rowoff[n] = run; wcur[n] = run; run += deg[n]; }
  }
  if (t == 1023) rowoff[NN] = s[1023];
}

__global__ __launch_bounds__(256) void fill_kernel(const int* __restrict__ ei,
                                                   int* __restrict__ wcur,
                                                   int* __restrict__ perm) {
  for (int e = blockIdx.x * 256 + threadIdx.x; e < NE; e += gridDim.x * 256) {
    int pos = atomicAdd(&wcur[ei[NE + e]], 1);
    perm[e] = pos;
  }
}

// ---------------- gather: linear CSR rows; per-block pstats (non-atomic) ----------------
template <typename T>
__global__ __launch_bounds__(256) void gather_kernel(
    const T* __restrict__ tp, const int* __restrict__ rowoff,
    const float* __restrict__ nf, float* __restrict__ pre,
    float* __restrict__ pstats)
{
  __shared__ float ls[40];
  const int tid = threadIdx.x;
  if (tid < 40) ls[tid] = 0.f;
  __syncthreads();
  const int wid = tid >> 6, lane = tid & 63;
  float sacc = 0.f, qacc = 0.f;
  if (lane < 40) {
#pragma unroll 1
    for (int i = 0; i < 4; ++i) {
      const int n = blockIdx.x * 16 + wid * 4 + i;   // GBLK*16 == NN exactly
      const int r0 = rowoff[n], r1 = rowoff[n + 1];
      float s0 = 0.f, s1 = 0.f, s2 = 0.f, s3 = 0.f,
            s4 = 0.f, s5 = 0.f, s6 = 0.f, s7 = 0.f;
      int k = r0;
      for (; k + 8 <= r1; k += 8) {
        s0 += TPS<T>::ld(tp + (size_t)(k + 0) * TPSTR + lane);
        s1 += TPS<T>::ld(tp + (size_t)(k + 1) * TPSTR + lane);
        s2 += TPS<T>::ld(tp + (size_t)(k + 2) * TPSTR + lane);
        s3 += TPS<T>::ld(tp + (size_t)(k + 3) * TPSTR + lane);
        s4 += TPS<T>::ld(tp + (size_t)(k + 4) * TPSTR + lane);
        s5 += TPS<T>::ld(tp + (size_t)(k + 5) * TPSTR + lane);
        s6 += TPS<T>::ld(tp + (size_t)(k + 6) * TPSTR + lane);
        s7 += TPS<T>::ld(tp + (size_t)(k + 7) * TPSTR + lane);
      }
      for (; k < r1; ++k) s0 += TPS<T>::ld(tp + (size_t)k * TPSTR + lane);
      float s = ((s0 + s1) + (s2 + s3)) + ((s4 + s5) + (s6 + s7));
      float val = s / fmaxf((float)(r1 - r0), 1.f) + nf[(size_t)n * 40 + lane];
      pre[(size_t)n * 40 + lane] = val;
      if (lane < 16) { sacc += val; qacc += val * val; }
      else qacc += val * val;
    }
    if (lane < 16) {
      atomicAdd(&ls[lane], sacc);
      atomicAdd(&ls[16 + lane], qacc);
    } else {
      atomicAdd(&ls[32 + (lane - 16) / 3], qacc);
    }
  }
  __syncthreads();
  if (tid < 40) pstats[(size_t)blockIdx.x * 40 + tid] = ls[tid];
}

// 40 blocks: channel c = blockIdx; sum 625 block-partials
__global__ __launch_bounds__(256) void stats_reduce(
    const float* __restrict__ pstats, float* __restrict__ stats)
{
  const int c = blockIdx.x;
  float s = 0.f;
  for (int i = threadIdx.x; i < GBLK; i += 256) s += pstats[(size_t)i * 40 + c];
#pragma unroll
  for (int off = 1; off < 64; off <<= 1) s += __shfl_xor(s, off);
  __shared__ float red[4];
  if ((threadIdx.x & 63) == 0) red[threadIdx.x >> 6] = s;
  __syncthreads();
  if (threadIdx.x == 0) stats[c] = (red[0] + red[1]) + (red[2] + red[3]);
}

__global__ __launch_bounds__(256) void node_pass2(
    const float* __restrict__ pre, const float* __restrict__ stats,
    const float* __restrict__ bnws, const float* __restrict__ bnbs,
    const float* __restrict__ bnwv, float* __restrict__ out)
{
  int idx = blockIdx.x * blockDim.x + threadIdx.x;
  if (idx >= NN * 40) return;
  int n = idx / 40;
  int c = idx - n * 40;
  float val = pre[idx];
  constexpr float invN = 1.0f / NN;
  if (c < 16) {
    float mu = stats[c] * invN;
    float var = stats[16 + c] * invN - mu * mu;
    out[idx] = (val - mu) * (rsqrtf(var + EPSV) * bnws[c]) + bnbs[c];
  } else {
    int u = (c - 16) / 3;
    float vn = stats[32 + u] * (invN / 3.0f);
    out[idx] = val * (rsqrtf(vn + EPSV) * bnwv[u]);
  }
}

__global__ __launch_bounds__(256) void copy_ef(const f32x4* __restrict__ src,
                                               f32x4* __restrict__ dst) {
  const int n4 = NE * 64 / 4;
  for (int i = blockIdx.x * blockDim.x + threadIdx.x; i < n4;
       i += gridDim.x * blockDim.x)
    dst[i] = src[i];
}

extern "C" void kernel_launch(void* const* d_in, const int* in_sizes, int n_in,
                              void* d_out, int out_size, void* d_ws, size_t ws_size,
                              hipStream_t stream) {
  (void)in_sizes; (void)n_in; (void)out_size;
  const float* nf   = (const float*)d_in[0];
  const float* ef   = (const float*)d_in[1];
  const float* sh   = (const float*)d_in[2];
  const int*   ei   = (const int*)d_in[3];
  const float* w1   = (const float*)d_in[4];
  const float* b1   = (const float*)d_in[5];
  const float* w2   = (const float*)d_in[6];
  const float* b2   = (const float*)d_in[7];
  const float* bnws = (const float*)d_in[8];
  const float* bnbs = (const float*)d_in[9];
  const float* bnwv = (const float*)d_in[10];

  float* out = (float*)d_out;
  float* efout = out + (size_t)NN * 40;

  // ws layout (no hfrag anymore)
  char* w = (char*)d_ws;
  int* deg     = (int*)w;                               // NN (zeroed by prep_w2)
  float* stats = (float*)(w + (size_t)NN * 4);          // 48 (written non-atomically)
  int* rowoff  = (int*)(w + (size_t)NN * 4 + 192);      // NN+1
  int* wcur    = rowoff + NN + 1;
  int* perm    = wcur + NN;                             // NE
  float* pre   = (float*)(perm + NE);                   // NN*40
  float* pstats = pre + (size_t)NN * 40;                // GBLK*40
  size_t base  = ((size_t)((char*)(pstats + (size_t)GBLK * 40) - w) + 255) & ~(size_t)255;
  short8* w2bf = (short8*)(w + base);                   // 73728 B
  size_t tpoff = (base + SM_W2 + 255) & ~(size_t)255;

  const size_t TPB_F32 = (size_t)NE * TPSTR * 4;        // 30.7 MB
  const size_t needA = tpoff + TPB_F32;

  hipFuncSetAttribute((const void*)conv_kernel<float>,
                      hipFuncAttributeMaxDynamicSharedMemorySize, SM_TOTAL);
  hipFuncSetAttribute((const void*)conv_kernel<ushort>,
                      hipFuncAttributeMaxDynamicSharedMemorySize, SM_TOTAL);

  prep_w2<<<72 + (NN + 63) / 64, 64, 0, stream>>>(w2, w2bf, deg);

  const int pblocks = (NN * 40 + 255) / 256;

  hist_kernel<<<625, 256, 0, stream>>>(ei, deg);
  scan_kernel<<<1, 1024, 0, stream>>>(deg, rowoff, wcur);
  fill_kernel<<<625, 256, 0, stream>>>(ei, wcur, perm);

  if (ws_size >= needA) {            // Plan A: f32 tp in ws; ef copy fused in conv
    float* tp = (float*)(w + tpoff);
    conv_kernel<float><<<256, 512, SM_TOTAL, stream>>>(
        ef, w1, b1, w2bf, b2, nf, sh, ei, perm, efout, 1, tp);
    gather_kernel<float><<<GBLK, 256, 0, stream>>>(tp, rowoff, nf, pre, pstats);
    stats_reduce<<<40, 256, 0, stream>>>(pstats, stats);
    node_pass2<<<pblocks, 256, 0, stream>>>(pre, stats, bnws, bnbs, bnwv, out);
  } else {                           // Plan D: bf16 tp in efout region; copy ef last
    ushort* tp = (ushort*)efout;                              // 15.4 MB
    conv_kernel<ushort><<<256, 512, SM_TOTAL, stream>>>(
        ef, w1, b1, w2bf, b2, nf, sh, ei, perm, efout, 0, tp);
    gather_kernel<ushort><<<GBLK, 256, 0, stream>>>(tp, rowoff, nf, pre, pstats);
    stats_reduce<<<40, 256, 0, stream>>>(pstats, stats);
    node_pass2<<<pblocks, 256, 0, stream>>>(pre, stats, bnws, bnbs, bnwv, out);
    copy_ef<<<2048, 256, 0, stream>>>((const f32x4*)ef, (f32x4*)efout);
  }
}

// Round 18
// 98.020 us; speedup vs baseline: 1.9258x; 1.0611x over previous
//
#include <hip/hip_runtime.h>

typedef __attribute__((ext_vector_type(8))) short short8;
typedef __attribute__((ext_vector_type(4))) float f32x4;
typedef __attribute__((ext_vector_type(4))) ushort u16x4;

constexpr int NN = 10000;
constexpr int NE = 160000;
constexpr int NT = NE / 16;                    // 10000 edge-tiles
constexpr int TPSTR = 48;                      // tp row stride (192 B = 3 lines)
constexpr int GBLK = 625;                      // gather blocks (625*16 = NN)
constexpr float EPSV = 1e-5f;
constexpr float INV3 = 0.57735026918962576f;   // 1/sqrt(3)
constexpr float ALPHA = 0.20412414523193152f;  // 1/sqrt(16+8)

__device__ __forceinline__ ushort f2bf(float x) {
  unsigned u = __float_as_uint(x);
  u += 0x7fffu + ((u >> 16) & 1u);
  return (ushort)(u >> 16);
}
__device__ __forceinline__ float bf2f(ushort u) {
  return __uint_as_float(((unsigned)u) << 16);
}
__device__ __forceinline__ f32x4 mfma16(short8 a, short8 b, f32x4 c) {
  return __builtin_amdgcn_mfma_f32_16x16x32_bf16(a, b, c, 0, 0, 0);
}

template <typename T> struct TPS;
template <> struct TPS<float> {
  static __device__ __forceinline__ void st4(float* p, f32x4 v) { *(f32x4*)p = v; }
  static __device__ __forceinline__ float ld(const float* p) { return *p; }
};
template <> struct TPS<ushort> {
  static __device__ __forceinline__ void st4(ushort* p, f32x4 v) {
    u16x4 o;
#pragma unroll
    for (int j = 0; j < 4; ++j) o[j] = f2bf(v[j]);
    *(u16x4*)p = o;
  }
  static __device__ __forceinline__ float ld(const ushort* p) { return bf2f(*p); }
};

// ---------------- K0: W2 -> bf16 A-frags; zero deg; b2 |max| flag ----------------
constexpr int PREP_DEGB = (NN + 63) / 64;      // 157
__global__ __launch_bounds__(64) void prep_w2(const float* __restrict__ w2,
                                              short8* __restrict__ w2bf,
                                              int* __restrict__ deg,
                                              const float* __restrict__ b2,
                                              float* __restrict__ flag) {
  int b = blockIdx.x;
  int lane = threadIdx.x;
  if (b < 72) {                // 72 = 36 jt * 2 kc
    int jt = b >> 1, kc = b & 1;
    int g = lane >> 4, c = lane & 15;
    short8 v;
#pragma unroll
    for (int j = 0; j < 8; ++j)
      v[j] = (short)f2bf(w2[(kc * 32 + 8 * g + j) * 576 + jt * 16 + c]);
    w2bf[(jt * 2 + kc) * 64 + lane] = v;
  } else if (b < 72 + PREP_DEGB) {
    int idx = (b - 72) * 64 + lane;
    if (idx < NN) deg[idx] = 0;
  } else {                     // last block: flag = max|b2|
    float m = 0.f;
    for (int i = lane; i < 576; i += 64) m = fmaxf(m, fabsf(b2[i]));
#pragma unroll
    for (int off = 1; off < 64; off <<= 1) m = fmaxf(m, __shfl_xor(m, off));
    if (lane == 0) *flag = m;
  }
}

// ---------------- K2: FUSED mlp1+conv (r17 body + r18 micro-opts) ----------------
// r18: (1) b2==0 fast path: d init 0, no b2lds read (-36 LDS b128/tile, no
// load->MFMA head dependency); (2) independent d0/d1 MFMA pair per jt
// (2x independent chains at 2 waves/SIMD); (3) cc vector reads for w00/w11.
constexpr int CSTR = 68;
constexpr unsigned SM_W2 = 4608 * 16;                       // 73728 B
constexpr unsigned SM_B2 = 576 * 4;                         // 2304 B
constexpr unsigned SM_W1 = 512 * 16;                        // 8192 B
constexpr unsigned SM_B1 = 64 * 4;                          // 256 B
constexpr unsigned SM_HL = 8 * 16 * 72 * 2;                 // 18432 B (transpose)
constexpr unsigned SM_SCR = 8 * 16 * CSTR * 4;              // 34816 B
constexpr unsigned SM_TOTAL = SM_W2 + SM_B2 + SM_W1 + SM_B1 + SM_HL + SM_SCR; // 137728

template <typename T>
__global__ __launch_bounds__(512) void conv_kernel(
    const float* __restrict__ ef, const float* __restrict__ w1,
    const float* __restrict__ b1, const short8* __restrict__ w2bf,
    const float* __restrict__ b2, const float* __restrict__ nf,
    const float* __restrict__ sh, const int* __restrict__ ei,
    const int* __restrict__ perm, float* __restrict__ efout, int do_copy,
    T* __restrict__ tp, const float* __restrict__ flagp)
{
  extern __shared__ char smem[];
  short8* w2lds = (short8*)smem;
  float*  b2lds = (float*)(smem + SM_W2);
  short8* w1f   = (short8*)(smem + SM_W2 + SM_B2);
  float*  b1lds = (float*)(smem + SM_W2 + SM_B2 + SM_W1);
  ushort* hlall = (ushort*)(smem + SM_W2 + SM_B2 + SM_W1 + SM_B1);
  float*  scrall = (float*)(smem + SM_W2 + SM_B2 + SM_W1 + SM_B1 + SM_HL);

  const int tid = threadIdx.x;
  for (int i = tid; i < 4608; i += 512) w2lds[i] = w2bf[i];
  for (int i = tid; i < 576; i += 512) b2lds[i] = b2[i];
  {  // W1 -> bf16 B-frags, one per thread (512 frags)
    int tile = tid >> 6, l = tid & 63;
    int nt = tile >> 1, kc = tile & 1;
    int gg = l >> 4, cc = l & 15;
    short8 v;
#pragma unroll
    for (int j = 0; j < 8; ++j)
      v[j] = (short)f2bf(w1[(kc * 32 + 8 * gg + j) * 64 + nt * 16 + cc]);
    w1f[tid] = v;
  }
  if (tid < 64) b1lds[tid] = b1[tid];
  const bool nob2 = (*flagp == 0.f);   // uniform
  __syncthreads();

  const int lane = tid & 63, wid = tid >> 6;
  const int g = lane >> 4, c = lane & 15;
  const int gh = g >> 1;
  const int e = lane >> 2, part = lane & 3;
  float* scr = scrall + wid * (16 * CSTR);
  ushort* hl = hlall + wid * (16 * 72);

  for (int t = blockIdx.x * 8 + wid; t < NT; t += gridDim.x * 8) {
    // ---- phase 0: issue gather loads early (latency hides under MLP1)
    const int ege = t * 16 + e;
    const float* __restrict__ src = nf + (size_t)ei[ege] * 40;
    const f32x4 sv = *(const f32x4*)(sh + (size_t)ege * 4);
    const f32x4 v0 = *(const f32x4*)(src + part * 4);
    const f32x4 v1 = *(const f32x4*)(src + 16 + part * 4);
    f32x4 v2 = {};
    if (part < 2) v2 = *(const f32x4*)(src + 32 + part * 4);

    // ---- phase 1: MLP1 GEMM (lane c = edge of this tile)
    const long ebase = (long)t * 16;
    short8 af[2];
    const float* rowp = ef + (ebase + c) * 64;
#pragma unroll
    for (int kc = 0; kc < 2; ++kc) {
      const f32x4* p = (const f32x4*)(rowp + kc * 32 + 8 * g);
      f32x4 lo = p[0], hi = p[1];
      if (do_copy) {
        f32x4* q = (f32x4*)(efout + (ebase + c) * 64 + kc * 32 + 8 * g);
        q[0] = lo; q[1] = hi;
      }
      short8 v;
#pragma unroll
      for (int j = 0; j < 4; ++j) { v[j] = (short)f2bf(lo[j]); v[4 + j] = (short)f2bf(hi[j]); }
      af[kc] = v;
    }
    f32x4 hacc[4] = {};
#pragma unroll
    for (int nt = 0; nt < 4; ++nt)
#pragma unroll
      for (int kc = 0; kc < 2; ++kc)
        hacc[nt] = mfma16(af[kc], w1f[(nt * 2 + kc) * 64 + lane], hacc[nt]);

    // ---- phase 2: bias+relu, per-wave LDS transpose -> h0/h1 (in-wave ordered)
#pragma unroll
    for (int nt = 0; nt < 4; ++nt) {
      float bv = b1lds[nt * 16 + c];
#pragma unroll
      for (int q = 0; q < 4; ++q) {
        float h = fmaxf(hacc[nt][q] + bv, 0.f);
        hl[(4 * g + q) * 72 + nt * 16 + c] = f2bf(h);
      }
    }
    const short8 h0 = *(const short8*)&hl[c * 72 + 8 * g];
    const short8 h1 = *(const short8*)&hl[c * 72 + 32 + 8 * g];

    // ---- phase 3: coefficient table from phase-0 regs (4 lanes per edge)
    {
      float* ce = scr + e * CSTR;
      f32x4 a0;
#pragma unroll
      for (int q = 0; q < 4; ++q) a0[q] = sv[0] * v0[q];
      *(f32x4*)(ce + 4 * part) = a0;
      *(f32x4*)(ce + 24 + 4 * part) = v0;
      *(f32x4*)(ce + 40 + 4 * part) = v1;
      if (part < 2) *(f32x4*)(ce + 56 + 4 * part) = v2;
#pragma unroll
      for (int uu = 0; uu < 2; ++uu) {
        int u = 2 * part + uu;
        ce[16 + u] = INV3 * (ce[40 + 3 * u] * sv[1] + ce[41 + 3 * u] * sv[2] +
                             ce[42 + 3 * u] * sv[3]);
      }
    }
    const float* __restrict__ cc = scr + c * CSTR;

    // ---- phase 4: j-GEMM + lane-local tensor product
    f32x4 out0acc = {0.f, 0.f, 0.f, 0.f};
    f32x4 c0acc = {0.f, 0.f, 0.f, 0.f};
    f32x4 c1acc[3] = {};

    if (nob2) {  // FAST PATH: zero-init d, independent d0/d1 chains
#pragma unroll
      for (int j4 = 0; j4 < 4; ++j4) {         // w00: u=jt, cc[0..15] vectorized
        const f32x4 a4 = *(const f32x4*)&cc[j4 * 4];
#pragma unroll
        for (int jj = 0; jj < 4; ++jj) {
          const int jt = j4 * 4 + jj;
          f32x4 z = {0.f, 0.f, 0.f, 0.f};
          f32x4 d0 = mfma16(w2lds[(jt * 2 + 0) * 64 + lane], h0, z);
          f32x4 d1 = mfma16(w2lds[(jt * 2 + 1) * 64 + lane], h1, z);
          float a = a4[jj];
#pragma unroll
          for (int q = 0; q < 4; ++q) {
            out0acc[q] = fmaf(a, d0[q], out0acc[q]);
            out0acc[q] = fmaf(a, d1[q], out0acc[q]);
          }
        }
      }
#pragma unroll
      for (int j4 = 0; j4 < 2; ++j4) {         // w11: u=jt-16, cc[16..23] vectorized
        const f32x4 a4 = *(const f32x4*)&cc[16 + j4 * 4];
#pragma unroll
        for (int jj = 0; jj < 4; ++jj) {
          const int jt = 16 + j4 * 4 + jj;
          f32x4 z = {0.f, 0.f, 0.f, 0.f};
          f32x4 d0 = mfma16(w2lds[(jt * 2 + 0) * 64 + lane], h0, z);
          f32x4 d1 = mfma16(w2lds[(jt * 2 + 1) * 64 + lane], h1, z);
          float a = a4[jj];
#pragma unroll
          for (int q = 0; q < 4; ++q) {
            out0acc[q] = fmaf(a, d0[q], out0acc[q]);
            out0acc[q] = fmaf(a, d1[q], out0acc[q]);
          }
        }
      }
#pragma unroll
      for (int jt = 24; jt < 32; ++jt) {       // w01: u=2(jt-24)+gh
        f32x4 z = {0.f, 0.f, 0.f, 0.f};
        f32x4 d0 = mfma16(w2lds[(jt * 2 + 0) * 64 + lane], h0, z);
        f32x4 d1 = mfma16(w2lds[(jt * 2 + 1) * 64 + lane], h1, z);
        float a = cc[24 + 2 * (jt - 24) + gh];
#pragma unroll
        for (int q = 0; q < 4; ++q) {
          c0acc[q] = fmaf(a, d0[q], c0acc[q]);
          c0acc[q] = fmaf(a, d1[q], c0acc[q]);
        }
      }
#pragma unroll
      for (int jt = 32; jt < 36; ++jt) {       // w10: u=2(jt-32)+gh
        f32x4 z = {0.f, 0.f, 0.f, 0.f};
        f32x4 d0 = mfma16(w2lds[(jt * 2 + 0) * 64 + lane], h0, z);
        f32x4 d1 = mfma16(w2lds[(jt * 2 + 1) * 64 + lane], h1, z);
        const int ub = 40 + 3 * (2 * (jt - 32) + gh);
#pragma unroll
        for (int i = 0; i < 3; ++i) {
          float a = cc[ub + i];
#pragma unroll
          for (int q = 0; q < 4; ++q) {
            c1acc[i][q] = fmaf(a, d0[q], c1acc[i][q]);
            c1acc[i][q] = fmaf(a, d1[q], c1acc[i][q]);
          }
        }
      }
    } else {     // GENERAL PATH (b2 != 0): r17 body, bias in C operand
#pragma unroll
      for (int jt = 0; jt < 16; ++jt) {
        f32x4 d = *(const f32x4*)&b2lds[jt * 16 + 4 * g];
        d = mfma16(w2lds[(jt * 2 + 0) * 64 + lane], h0, d);
        d = mfma16(w2lds[(jt * 2 + 1) * 64 + lane], h1, d);
        float a = cc[jt];
#pragma unroll
        for (int q = 0; q < 4; ++q) out0acc[q] = fmaf(a, d[q], out0acc[q]);
      }
#pragma unroll
      for (int jt = 16; jt < 24; ++jt) {
        f32x4 d = *(const f32x4*)&b2lds[jt * 16 + 4 * g];
        d = mfma16(w2lds[(jt * 2 + 0) * 64 + lane], h0, d);
        d = mfma16(w2lds[(jt * 2 + 1) * 64 + lane], h1, d);
        float a = cc[16 + (jt - 16)];
#pragma unroll
        for (int q = 0; q < 4; ++q) out0acc[q] = fmaf(a, d[q], out0acc[q]);
      }
#pragma unroll
      for (int jt = 24; jt < 32; ++jt) {
        f32x4 d = *(const f32x4*)&b2lds[jt * 16 + 4 * g];
        d = mfma16(w2lds[(jt * 2 + 0) * 64 + lane], h0, d);
        d = mfma16(w2lds[(jt * 2 + 1) * 64 + lane], h1, d);
        float a = cc[24 + 2 * (jt - 24) + gh];
#pragma unroll
        for (int q = 0; q < 4; ++q) c0acc[q] = fmaf(a, d[q], c0acc[q]);
      }
#pragma unroll
      for (int jt = 32; jt < 36; ++jt) {
        f32x4 d = *(const f32x4*)&b2lds[jt * 16 + 4 * g];
        d = mfma16(w2lds[(jt * 2 + 0) * 64 + lane], h0, d);
        d = mfma16(w2lds[(jt * 2 + 1) * 64 + lane], h1, d);
        const int ub = 40 + 3 * (2 * (jt - 32) + gh);
#pragma unroll
        for (int i = 0; i < 3; ++i) {
          float a = cc[ub + i];
#pragma unroll
          for (int q = 0; q < 4; ++q) c1acc[i][q] = fmaf(a, d[q], c1acc[i][q]);
        }
      }
    }

    // fold gh halves (lane ^ 32)
#pragma unroll
    for (int q = 0; q < 4; ++q) c0acc[q] += __shfl_xor(c0acc[q], 32);
#pragma unroll
    for (int i = 0; i < 3; ++i)
#pragma unroll
      for (int q = 0; q < 4; ++q) c1acc[i][q] += __shfl_xor(c1acc[i][q], 32);

    // store into this edge's CSR slot (scattered rows, line-aligned 192 B)
    const int eg = t * 16 + c;
    const f32x4 shv = *(const f32x4*)(sh + (size_t)eg * 4);
    T* tpr = tp + (size_t)perm[eg] * TPSTR;
    f32x4 o0;
#pragma unroll
    for (int q = 0; q < 4; ++q) o0[q] = ALPHA * out0acc[q];
    TPS<T>::st4(tpr + 4 * g, o0);
    if (g < 2) {
      float wv[12];
#pragma unroll
      for (int q = 0; q < 4; ++q)
#pragma unroll
        for (int i = 0; i < 3; ++i)
          wv[q * 3 + i] = ALPHA * (shv[1 + i] * c0acc[q] + shv[0] * c1acc[i][q]);
#pragma unroll
      for (int p = 0; p < 3; ++p) {
        f32x4 v = {wv[4 * p], wv[4 * p + 1], wv[4 * p + 2], wv[4 * p + 3]};
        TPS<T>::st4(tpr + 16 + 12 * g + 4 * p, v);
      }
    }
  }
}

// ---------------- CSR build ----------------
__global__ __launch_bounds__(256) void hist_kernel(const int* __restrict__ ei,
                                                   int* __restrict__ deg) {
  for (int e = blockIdx.x * 256 + threadIdx.x; e < NE; e += gridDim.x * 256)
    atomicAdd(&deg[ei[NE + e]], 1);
}

__global__ __launch_bounds__(1024) void scan_kernel(const int* __restrict__ deg,
                                                    int* __restrict__ rowoff,
                                                    int* __restrict__ wcur) {
  __shared__ int s[1024];
  int t = threadIdx.x;
  int base = t * 10;
  int sum = 0;
#pragma unroll
  for (int j = 0; j < 10; ++j) { int n = base + j; sum += (n < NN) ? deg[n] : 0; }
  s[t] = sum;
  __syncthreads();
  for (int off = 1; off < 1024; off <<= 1) {
    int v = (t >= off) ? s[t - off] : 0;
    __syncthreads();
    s[t] += v;
    __syncthreads();
  }
  int run = s[t] - sum;
#pragma unroll
  for (int j = 0; j < 10; ++j) {
    int n = base + j;
    if (n < NN) { rowoff[n] = run; wcur[n] = run; run += deg[n]; }
  }
  if (t == 1023) rowoff[NN] = s[1023];
}

__global__ __launch_bounds__(256) void fill_kernel(const int* __restrict__ ei,
                                                   int* __restrict__ wcur,
                                                   int* __restrict__ perm) {
  for (int e = blockIdx.x * 256 + threadIdx.x; e < NE; e += gridDim.x * 256) {
    int pos = atomicAdd(&wcur[ei[NE + e]], 1);
    perm[e] = pos;
  }
}

// ---------------- gather: linear CSR rows; per-block pstats (non-atomic) ----------------
template <typename T>
__global__ __launch_bounds__(256) void gather_kernel(
    const T* __restrict__ tp, const int* __restrict__ rowoff,
    const float* __restrict__ nf, float* __restrict__ pre,
    float* __restrict__ pstats)
{
  __shared__ float ls[40];
  const int tid = threadIdx.x;
  if (tid < 40) ls[tid] = 0.f;
  __syncthreads();
  const int wid = tid >> 6, lane = tid & 63;
  float sacc = 0.f, qacc = 0.f;
  if (lane < 40) {
#pragma unroll 1
    for (int i = 0; i < 4; ++i) {
      const int n = blockIdx.x * 16 + wid * 4 + i;   // GBLK*16 == NN exactly
      const int r0 = rowoff[n], r1 = rowoff[n + 1];
      float s0 = 0.f, s1 = 0.f, s2 = 0.f, s3 = 0.f,
            s4 = 0.f, s5 = 0.f, s6 = 0.f, s7 = 0.f;
      int k = r0;
      for (; k + 8 <= r1; k += 8) {
        s0 += TPS<T>::ld(tp + (size_t)(k + 0) * TPSTR + lane);
        s1 += TPS<T>::ld(tp + (size_t)(k + 1) * TPSTR + lane);
        s2 += TPS<T>::ld(tp + (size_t)(k + 2) * TPSTR + lane);
        s3 += TPS<T>::ld(tp + (size_t)(k + 3) * TPSTR + lane);
        s4 += TPS<T>::ld(tp + (size_t)(k + 4) * TPSTR + lane);
        s5 += TPS<T>::ld(tp + (size_t)(k + 5) * TPSTR + lane);
        s6 += TPS<T>::ld(tp + (size_t)(k + 6) * TPSTR + lane);
        s7 += TPS<T>::ld(tp + (size_t)(k + 7) * TPSTR + lane);
      }
      for (; k < r1; ++k) s0 += TPS<T>::ld(tp + (size_t)k * TPSTR + lane);
      float s = ((s0 + s1) + (s2 + s3)) + ((s4 + s5) + (s6 + s7));
      float val = s / fmaxf((float)(r1 - r0), 1.f) + nf[(size_t)n * 40 + lane];
      pre[(size_t)n * 40 + lane] = val;
      if (lane < 16) { sacc += val; qacc += val * val; }
      else qacc += val * val;
    }
    if (lane < 16) {
      atomicAdd(&ls[lane], sacc);
      atomicAdd(&ls[16 + lane], qacc);
    } else {
      atomicAdd(&ls[32 + (lane - 16) / 3], qacc);
    }
  }
  __syncthreads();
  if (tid < 40) pstats[(size_t)blockIdx.x * 40 + tid] = ls[tid];
}

// 40 blocks: channel c = blockIdx; sum 625 block-partials
__global__ __launch_bounds__(256) void stats_reduce(
    const float* __restrict__ pstats, float* __restrict__ stats)
{
  const int c = blockIdx.x;
  float s = 0.f;
  for (int i = threadIdx.x; i < GBLK; i += 256) s += pstats[(size_t)i * 40 + c];
#pragma unroll
  for (int off = 1; off < 64; off <<= 1) s += __shfl_xor(s, off);
  __shared__ float red[4];
  if ((threadIdx.x & 63) == 0) red[threadIdx.x >> 6] = s;
  __syncthreads();
  if (threadIdx.x == 0) stats[c] = (red[0] + red[1]) + (red[2] + red[3]);
}

__global__ __launch_bounds__(256) void node_pass2(
    const float* __restrict__ pre, const float* __restrict__ stats,
    const float* __restrict__ bnws, const float* __restrict__ bnbs,
    const float* __restrict__ bnwv, float* __restrict__ out)
{
  int idx = blockIdx.x * blockDim.x + threadIdx.x;
  if (idx >= NN * 40) return;
  int n = idx / 40;
  int c = idx - n * 40;
  float val = pre[idx];
  constexpr float invN = 1.0f / NN;
  if (c < 16) {
    float mu = stats[c] * invN;
    float var = stats[16 + c] * invN - mu * mu;
    out[idx] = (val - mu) * (rsqrtf(var + EPSV) * bnws[c]) + bnbs[c];
  } else {
    int u = (c - 16) / 3;
    float vn = stats[32 + u] * (invN / 3.0f);
    out[idx] = val * (rsqrtf(vn + EPSV) * bnwv[u]);
  }
}

__global__ __launch_bounds__(256) void copy_ef(const f32x4* __restrict__ src,
                                               f32x4* __restrict__ dst) {
  const int n4 = NE * 64 / 4;
  for (int i = blockIdx.x * blockDim.x + threadIdx.x; i < n4;
       i += gridDim.x * blockDim.x)
    dst[i] = src[i];
}

extern "C" void kernel_launch(void* const* d_in, const int* in_sizes, int n_in,
                              void* d_out, int out_size, void* d_ws, size_t ws_size,
                              hipStream_t stream) {
  (void)in_sizes; (void)n_in; (void)out_size;
  const float* nf   = (const float*)d_in[0];
  const float* ef   = (const float*)d_in[1];
  const float* sh   = (const float*)d_in[2];
  const int*   ei   = (const int*)d_in[3];
  const float* w1   = (const float*)d_in[4];
  const float* b1   = (const float*)d_in[5];
  const float* w2   = (const float*)d_in[6];
  const float* b2   = (const float*)d_in[7];
  const float* bnws = (const float*)d_in[8];
  const float* bnbs = (const float*)d_in[9];
  const float* bnwv = (const float*)d_in[10];

  float* out = (float*)d_out;
  float* efout = out + (size_t)NN * 40;

  // ws layout
  char* w = (char*)d_ws;
  int* deg     = (int*)w;                               // NN (zeroed by prep_w2)
  float* stats = (float*)(w + (size_t)NN * 4);          // 40; [44] = b2 flag
  float* flag  = stats + 44;
  int* rowoff  = (int*)(w + (size_t)NN * 4 + 192);      // NN+1
  int* wcur    = rowoff + NN + 1;
  int* perm    = wcur + NN;                             // NE
  float* pre   = (float*)(perm + NE);                   // NN*40
  float* pstats = pre + (size_t)NN * 40;                // GBLK*40
  size_t base  = ((size_t)((char*)(pstats + (size_t)GBLK * 40) - w) + 255) & ~(size_t)255;
  short8* w2bf = (short8*)(w + base);                   // 73728 B
  size_t tpoff = (base + SM_W2 + 255) & ~(size_t)255;

  const size_t TPB_F32 = (size_t)NE * TPSTR * 4;        // 30.7 MB
  const size_t needA = tpoff + TPB_F32;

  hipFuncSetAttribute((const void*)conv_kernel<float>,
                      hipFuncAttributeMaxDynamicSharedMemorySize, SM_TOTAL);
  hipFuncSetAttribute((const void*)conv_kernel<ushort>,
                      hipFuncAttributeMaxDynamicSharedMemorySize, SM_TOTAL);

  prep_w2<<<72 + PREP_DEGB + 1, 64, 0, stream>>>(w2, w2bf, deg, b2, flag);

  const int pblocks = (NN * 40 + 255) / 256;

  hist_kernel<<<625, 256, 0, stream>>>(ei, deg);
  scan_kernel<<<1, 1024, 0, stream>>>(deg, rowoff, wcur);
  fill_kernel<<<625, 256, 0, stream>>>(ei, wcur, perm);

  if (ws_size >= needA) {            // Plan A: f32 tp in ws; ef copy fused in conv
    float* tp = (float*)(w + tpoff);
    conv_kernel<float><<<256, 512, SM_TOTAL, stream>>>(
        ef, w1, b1, w2bf, b2, nf, sh, ei, perm, efout, 1, tp, flag);
    gather_kernel<float><<<GBLK, 256, 0, stream>>>(tp, rowoff, nf, pre, pstats);
    stats_reduce<<<40, 256, 0, stream>>>(pstats, stats);
    node_pass2<<<pblocks, 256, 0, stream>>>(pre, stats, bnws, bnbs, bnwv, out);
  } else {                           // Plan D: bf16 tp in efout region; copy ef last
    ushort* tp = (ushort*)efout;                              // 15.4 MB
    conv_kernel<ushort><<<256, 512, SM_TOTAL, stream>>>(
        ef, w1, b1, w2bf, b2, nf, sh, ei, perm, efout, 0, tp, flag);
    gather_kernel<ushort><<<GBLK, 256, 0, stream>>>(tp, rowoff, nf, pre, pstats);
    stats_reduce<<<40, 256, 0, stream>>>(pstats, stats);
    node_pass2<<<pblocks, 256, 0, stream>>>(pre, stats, bnws, bnbs, bnwv, out);
    copy_ef<<<2048, 256, 0, stream>>>((const f32x4*)ef, (f32x4*)efout);
  }
}

// Round 19
// 95.243 us; speedup vs baseline: 1.9819x; 1.0292x over previous
//
#include <hip/hip_runtime.h>

typedef __attribute__((ext_vector_type(8))) short short8;
typedef __attribute__((ext_vector_type(4))) float f32x4;
typedef __attribute__((ext_vector_type(4))) ushort u16x4;

constexpr int NN = 10000;
constexpr int NE = 160000;
constexpr int NT = NE / 16;                    // 10000 edge-tiles
constexpr int TPSTR = 64;                      // tp row stride in USHORT (128 B = 2 lines)
constexpr int GBLK = 625;                      // gather blocks (625*16 = NN)
constexpr float EPSV = 1e-5f;
constexpr float INV3 = 0.57735026918962576f;   // 1/sqrt(3)
constexpr float ALPHA = 0.20412414523193152f;  // 1/sqrt(16+8)

__device__ __forceinline__ ushort f2bf(float x) {
  unsigned u = __float_as_uint(x);
  u += 0x7fffu + ((u >> 16) & 1u);
  return (ushort)(u >> 16);
}
__device__ __forceinline__ float bf2f(ushort u) {
  return __uint_as_float(((unsigned)u) << 16);
}
__device__ __forceinline__ f32x4 mfma16(short8 a, short8 b, f32x4 c) {
  return __builtin_amdgcn_mfma_f32_16x16x32_bf16(a, b, c, 0, 0, 0);
}
__device__ __forceinline__ void st4u(ushort* p, f32x4 v) {
  u16x4 o;
#pragma unroll
  for (int j = 0; j < 4; ++j) o[j] = f2bf(v[j]);
  *(u16x4*)p = o;
}

// ---------------- K0: W2 -> bf16 A-frags; zero deg; b2 |max| flag ----------------
constexpr int PREP_DEGB = (NN + 63) / 64;      // 157
__global__ __launch_bounds__(64) void prep_w2(const float* __restrict__ w2,
                                              short8* __restrict__ w2bf,
                                              int* __restrict__ deg,
                                              const float* __restrict__ b2,
                                              float* __restrict__ flag) {
  int b = blockIdx.x;
  int lane = threadIdx.x;
  if (b < 72) {                // 72 = 36 jt * 2 kc
    int jt = b >> 1, kc = b & 1;
    int g = lane >> 4, c = lane & 15;
    short8 v;
#pragma unroll
    for (int j = 0; j < 8; ++j)
      v[j] = (short)f2bf(w2[(kc * 32 + 8 * g + j) * 576 + jt * 16 + c]);
    w2bf[(jt * 2 + kc) * 64 + lane] = v;
  } else if (b < 72 + PREP_DEGB) {
    int idx = (b - 72) * 64 + lane;
    if (idx < NN) deg[idx] = 0;
  } else {                     // last block: flag = max|b2|
    float m = 0.f;
    for (int i = lane; i < 576; i += 64) m = fmaxf(m, fabsf(b2[i]));
#pragma unroll
    for (int off = 1; off < 64; off <<= 1) m = fmaxf(m, __shfl_xor(m, off));
    if (lane == 0) *flag = m;
  }
}

// ---------------- K2: FUSED mlp1+conv (r18 proven body; bf16 tp out) ----------------
constexpr int CSTR = 68;
constexpr unsigned SM_W2 = 4608 * 16;                       // 73728 B
constexpr unsigned SM_B2 = 576 * 4;                         // 2304 B
constexpr unsigned SM_W1 = 512 * 16;                        // 8192 B
constexpr unsigned SM_B1 = 64 * 4;                          // 256 B
constexpr unsigned SM_HL = 8 * 16 * 72 * 2;                 // 18432 B (transpose)
constexpr unsigned SM_SCR = 8 * 16 * CSTR * 4;              // 34816 B
constexpr unsigned SM_TOTAL = SM_W2 + SM_B2 + SM_W1 + SM_B1 + SM_HL + SM_SCR; // 137728

__global__ __launch_bounds__(512) void conv_kernel(
    const float* __restrict__ ef, const float* __restrict__ w1,
    const float* __restrict__ b1, const short8* __restrict__ w2bf,
    const float* __restrict__ b2, const float* __restrict__ nf,
    const float* __restrict__ sh, const int* __restrict__ ei,
    const int* __restrict__ perm, float* __restrict__ efout, int do_copy,
    ushort* __restrict__ tp, const float* __restrict__ flagp)
{
  extern __shared__ char smem[];
  short8* w2lds = (short8*)smem;
  float*  b2lds = (float*)(smem + SM_W2);
  short8* w1f   = (short8*)(smem + SM_W2 + SM_B2);
  float*  b1lds = (float*)(smem + SM_W2 + SM_B2 + SM_W1);
  ushort* hlall = (ushort*)(smem + SM_W2 + SM_B2 + SM_W1 + SM_B1);
  float*  scrall = (float*)(smem + SM_W2 + SM_B2 + SM_W1 + SM_B1 + SM_HL);

  const int tid = threadIdx.x;
  for (int i = tid; i < 4608; i += 512) w2lds[i] = w2bf[i];
  for (int i = tid; i < 576; i += 512) b2lds[i] = b2[i];
  {  // W1 -> bf16 B-frags, one per thread (512 frags)
    int tile = tid >> 6, l = tid & 63;
    int nt = tile >> 1, kc = tile & 1;
    int gg = l >> 4, cc = l & 15;
    short8 v;
#pragma unroll
    for (int j = 0; j < 8; ++j)
      v[j] = (short)f2bf(w1[(kc * 32 + 8 * gg + j) * 64 + nt * 16 + cc]);
    w1f[tid] = v;
  }
  if (tid < 64) b1lds[tid] = b1[tid];
  const bool nob2 = (*flagp == 0.f);   // uniform
  __syncthreads();

  const int lane = tid & 63, wid = tid >> 6;
  const int g = lane >> 4, c = lane & 15;
  const int gh = g >> 1;
  const int e = lane >> 2, part = lane & 3;
  float* scr = scrall + wid * (16 * CSTR);
  ushort* hl = hlall + wid * (16 * 72);

  for (int t = blockIdx.x * 8 + wid; t < NT; t += gridDim.x * 8) {
    // ---- phase 0: issue gather loads early (latency hides under MLP1)
    const int ege = t * 16 + e;
    const float* __restrict__ src = nf + (size_t)ei[ege] * 40;
    const f32x4 sv = *(const f32x4*)(sh + (size_t)ege * 4);
    const f32x4 v0 = *(const f32x4*)(src + part * 4);
    const f32x4 v1 = *(const f32x4*)(src + 16 + part * 4);
    f32x4 v2 = {};
    if (part < 2) v2 = *(const f32x4*)(src + 32 + part * 4);

    // ---- phase 1: MLP1 GEMM (lane c = edge of this tile)
    const long ebase = (long)t * 16;
    short8 af[2];
    const float* rowp = ef + (ebase + c) * 64;
#pragma unroll
    for (int kc = 0; kc < 2; ++kc) {
      const f32x4* p = (const f32x4*)(rowp + kc * 32 + 8 * g);
      f32x4 lo = p[0], hi = p[1];
      if (do_copy) {
        f32x4* q = (f32x4*)(efout + (ebase + c) * 64 + kc * 32 + 8 * g);
        q[0] = lo; q[1] = hi;
      }
      short8 v;
#pragma unroll
      for (int j = 0; j < 4; ++j) { v[j] = (short)f2bf(lo[j]); v[4 + j] = (short)f2bf(hi[j]); }
      af[kc] = v;
    }
    f32x4 hacc[4] = {};
#pragma unroll
    for (int nt = 0; nt < 4; ++nt)
#pragma unroll
      for (int kc = 0; kc < 2; ++kc)
        hacc[nt] = mfma16(af[kc], w1f[(nt * 2 + kc) * 64 + lane], hacc[nt]);

    // ---- phase 2: bias+relu, per-wave LDS transpose -> h0/h1 (in-wave ordered)
#pragma unroll
    for (int nt = 0; nt < 4; ++nt) {
      float bv = b1lds[nt * 16 + c];
#pragma unroll
      for (int q = 0; q < 4; ++q) {
        float h = fmaxf(hacc[nt][q] + bv, 0.f);
        hl[(4 * g + q) * 72 + nt * 16 + c] = f2bf(h);
      }
    }
    const short8 h0 = *(const short8*)&hl[c * 72 + 8 * g];
    const short8 h1 = *(const short8*)&hl[c * 72 + 32 + 8 * g];

    // ---- phase 3: coefficient table from phase-0 regs (4 lanes per edge)
    {
      float* ce = scr + e * CSTR;
      f32x4 a0;
#pragma unroll
      for (int q = 0; q < 4; ++q) a0[q] = sv[0] * v0[q];
      *(f32x4*)(ce + 4 * part) = a0;
      *(f32x4*)(ce + 24 + 4 * part) = v0;
      *(f32x4*)(ce + 40 + 4 * part) = v1;
      if (part < 2) *(f32x4*)(ce + 56 + 4 * part) = v2;
#pragma unroll
      for (int uu = 0; uu < 2; ++uu) {
        int u = 2 * part + uu;
        ce[16 + u] = INV3 * (ce[40 + 3 * u] * sv[1] + ce[41 + 3 * u] * sv[2] +
                             ce[42 + 3 * u] * sv[3]);
      }
    }
    const float* __restrict__ cc = scr + c * CSTR;

    // ---- phase 4: j-GEMM + lane-local tensor product
    f32x4 out0acc = {0.f, 0.f, 0.f, 0.f};
    f32x4 c0acc = {0.f, 0.f, 0.f, 0.f};
    f32x4 c1acc[3] = {};

    if (nob2) {  // FAST PATH: zero-init d, independent d0/d1 chains
#pragma unroll
      for (int j4 = 0; j4 < 4; ++j4) {         // w00: u=jt, cc[0..15] vectorized
        const f32x4 a4 = *(const f32x4*)&cc[j4 * 4];
#pragma unroll
        for (int jj = 0; jj < 4; ++jj) {
          const int jt = j4 * 4 + jj;
          f32x4 z = {0.f, 0.f, 0.f, 0.f};
          f32x4 d0 = mfma16(w2lds[(jt * 2 + 0) * 64 + lane], h0, z);
          f32x4 d1 = mfma16(w2lds[(jt * 2 + 1) * 64 + lane], h1, z);
          float a = a4[jj];
#pragma unroll
          for (int q = 0; q < 4; ++q) {
            out0acc[q] = fmaf(a, d0[q], out0acc[q]);
            out0acc[q] = fmaf(a, d1[q], out0acc[q]);
          }
        }
      }
#pragma unroll
      for (int j4 = 0; j4 < 2; ++j4) {         // w11: u=jt-16, cc[16..23] vectorized
        const f32x4 a4 = *(const f32x4*)&cc[16 + j4 * 4];
#pragma unroll
        for (int jj = 0; jj < 4; ++jj) {
          const int jt = 16 + j4 * 4 + jj;
          f32x4 z = {0.f, 0.f, 0.f, 0.f};
          f32x4 d0 = mfma16(w2lds[(jt * 2 + 0) * 64 + lane], h0, z);
          f32x4 d1 = mfma16(w2lds[(jt * 2 + 1) * 64 + lane], h1, z);
          float a = a4[jj];
#pragma unroll
          for (int q = 0; q < 4; ++q) {
            out0acc[q] = fmaf(a, d0[q], out0acc[q]);
            out0acc[q] = fmaf(a, d1[q], out0acc[q]);
          }
        }
      }
#pragma unroll
      for (int jt = 24; jt < 32; ++jt) {       // w01: u=2(jt-24)+gh
        f32x4 z = {0.f, 0.f, 0.f, 0.f};
        f32x4 d0 = mfma16(w2lds[(jt * 2 + 0) * 64 + lane], h0, z);
        f32x4 d1 = mfma16(w2lds[(jt * 2 + 1) * 64 + lane], h1, z);
        float a = cc[24 + 2 * (jt - 24) + gh];
#pragma unroll
        for (int q = 0; q < 4; ++q) {
          c0acc[q] = fmaf(a, d0[q], c0acc[q]);
          c0acc[q] = fmaf(a, d1[q], c0acc[q]);
        }
      }
#pragma unroll
      for (int jt = 32; jt < 36; ++jt) {       // w10: u=2(jt-32)+gh
        f32x4 z = {0.f, 0.f, 0.f, 0.f};
        f32x4 d0 = mfma16(w2lds[(jt * 2 + 0) * 64 + lane], h0, z);
        f32x4 d1 = mfma16(w2lds[(jt * 2 + 1) * 64 + lane], h1, z);
        const int ub = 40 + 3 * (2 * (jt - 32) + gh);
#pragma unroll
        for (int i = 0; i < 3; ++i) {
          float a = cc[ub + i];
#pragma unroll
          for (int q = 0; q < 4; ++q) {
            c1acc[i][q] = fmaf(a, d0[q], c1acc[i][q]);
            c1acc[i][q] = fmaf(a, d1[q], c1acc[i][q]);
          }
        }
      }
    } else {     // GENERAL PATH (b2 != 0): bias in C operand
#pragma unroll
      for (int jt = 0; jt < 16; ++jt) {
        f32x4 d = *(const f32x4*)&b2lds[jt * 16 + 4 * g];
        d = mfma16(w2lds[(jt * 2 + 0) * 64 + lane], h0, d);
        d = mfma16(w2lds[(jt * 2 + 1) * 64 + lane], h1, d);
        float a = cc[jt];
#pragma unroll
        for (int q = 0; q < 4; ++q) out0acc[q] = fmaf(a, d[q], out0acc[q]);
      }
#pragma unroll
      for (int jt = 16; jt < 24; ++jt) {
        f32x4 d = *(const f32x4*)&b2lds[jt * 16 + 4 * g];
        d = mfma16(w2lds[(jt * 2 + 0) * 64 + lane], h0, d);
        d = mfma16(w2lds[(jt * 2 + 1) * 64 + lane], h1, d);
        float a = cc[16 + (jt - 16)];
#pragma unroll
        for (int q = 0; q < 4; ++q) out0acc[q] = fmaf(a, d[q], out0acc[q]);
      }
#pragma unroll
      for (int jt = 24; jt < 32; ++jt) {
        f32x4 d = *(const f32x4*)&b2lds[jt * 16 + 4 * g];
        d = mfma16(w2lds[(jt * 2 + 0) * 64 + lane], h0, d);
        d = mfma16(w2lds[(jt * 2 + 1) * 64 + lane], h1, d);
        float a = cc[24 + 2 * (jt - 24) + gh];
#pragma unroll
        for (int q = 0; q < 4; ++q) c0acc[q] = fmaf(a, d[q], c0acc[q]);
      }
#pragma unroll
      for (int jt = 32; jt < 36; ++jt) {
        f32x4 d = *(const f32x4*)&b2lds[jt * 16 + 4 * g];
        d = mfma16(w2lds[(jt * 2 + 0) * 64 + lane], h0, d);
        d = mfma16(w2lds[(jt * 2 + 1) * 64 + lane], h1, d);
        const int ub = 40 + 3 * (2 * (jt - 32) + gh);
#pragma unroll
        for (int i = 0; i < 3; ++i) {
          float a = cc[ub + i];
#pragma unroll
          for (int q = 0; q < 4; ++q) c1acc[i][q] = fmaf(a, d[q], c1acc[i][q]);
        }
      }
    }

    // fold gh halves (lane ^ 32)
#pragma unroll
    for (int q = 0; q < 4; ++q) c0acc[q] += __shfl_xor(c0acc[q], 32);
#pragma unroll
    for (int i = 0; i < 3; ++i)
#pragma unroll
      for (int q = 0; q < 4; ++q) c1acc[i][q] += __shfl_xor(c1acc[i][q], 32);

    // store into this edge's CSR slot (bf16 rows, 128 B line-pair aligned)
    const int eg = t * 16 + c;
    const f32x4 shv = *(const f32x4*)(sh + (size_t)eg * 4);
    ushort* tpr = tp + (size_t)perm[eg] * TPSTR;
    f32x4 o0;
#pragma unroll
    for (int q = 0; q < 4; ++q) o0[q] = ALPHA * out0acc[q];
    st4u(tpr + 4 * g, o0);
    if (g < 2) {
      float wv[12];
#pragma unroll
      for (int q = 0; q < 4; ++q)
#pragma unroll
        for (int i = 0; i < 3; ++i)
          wv[q * 3 + i] = ALPHA * (shv[1 + i] * c0acc[q] + shv[0] * c1acc[i][q]);
#pragma unroll
      for (int p = 0; p < 3; ++p) {
        f32x4 v = {wv[4 * p], wv[4 * p + 1], wv[4 * p + 2], wv[4 * p + 3]};
        st4u(tpr + 16 + 12 * g + 4 * p, v);
      }
    }
  }
}

// ---------------- CSR build ----------------
__global__ __launch_bounds__(256) void hist_kernel(const int* __restrict__ ei,
                                                   int* __restrict__ deg) {
  for (int e = blockIdx.x * 256 + threadIdx.x; e < NE; e += gridDim.x * 256)
    atomicAdd(&deg[ei[NE + e]], 1);
}

// r19: wave-level shfl_up scan, 2 barriers total (was 20-barrier Hillis-Steele)
__global__ __launch_bounds__(1024) void scan_kernel(const int* __restrict__ deg,
                                                    int* __restrict__ rowoff,
                                                    int* __restrict__ wcur) {
  __shared__ int wsum[16];
  const int t = threadIdx.x;
  const int lane = t & 63, wid = t >> 6;
  const int base = t * 10;
  int d[10];
  int sum = 0;
#pragma unroll
  for (int j = 0; j < 10; ++j) {
    int n = base + j;
    d[j] = (n < NN) ? deg[n] : 0;
    sum += d[j];
  }
  int val = sum;                       // inclusive scan within wave
#pragma unroll
  for (int off = 1; off < 64; off <<= 1) {
    int v = __shfl_up(val, off);
    if (lane >= off) val += v;
  }
  if (lane == 63) wsum[wid] = val;
  __syncthreads();
  if (t < 16) {
    int v = wsum[t];
#pragma unroll
    for (int off = 1; off < 16; off <<= 1) {
      int u = __shfl_up(v, off);
      if (t >= off) v += u;
    }
    wsum[t] = v;                       // inclusive over waves
  }
  __syncthreads();
  const int waveoff = (wid > 0) ? wsum[wid - 1] : 0;
  int run = waveoff + (val - sum);     // exclusive prefix for this thread
#pragma unroll
  for (int j = 0; j < 10; ++j) {
    int n = base + j;
    if (n < NN) { rowoff[n] = run; wcur[n] = run; }
    run += d[j];
  }
  if (t == 1023) rowoff[NN] = run;
}

__global__ __launch_bounds__(256) void fill_kernel(const int* __restrict__ ei,
                                                   int* __restrict__ wcur,
                                                   int* __restrict__ perm) {
  for (int e = blockIdx.x * 256 + threadIdx.x; e < NE; e += gridDim.x * 256) {
    int pos = atomicAdd(&wcur[ei[NE + e]], 1);
    perm[e] = pos;
  }
}

// ---------------- gather: linear CSR bf16 rows; per-block pstats (non-atomic) ----------------
__global__ __launch_bounds__(256) void gather_kernel(
    const ushort* __restrict__ tp, const int* __restrict__ rowoff,
    const float* __restrict__ nf, float* __restrict__ pre,
    float* __restrict__ pstats)
{
  __shared__ float ls[40];
  const int tid = threadIdx.x;
  if (tid < 40) ls[tid] = 0.f;
  __syncthreads();
  const int wid = tid >> 6, lane = tid & 63;
  float sacc = 0.f, qacc = 0.f;
  if (lane < 40) {
#pragma unroll 1
    for (int i = 0; i < 4; ++i) {
      const int n = blockIdx.x * 16 + wid * 4 + i;   // GBLK*16 == NN exactly
      const int r0 = rowoff[n], r1 = rowoff[n + 1];
      float s0 = 0.f, s1 = 0.f, s2 = 0.f, s3 = 0.f,
            s4 = 0.f, s5 = 0.f, s6 = 0.f, s7 = 0.f;
      int k = r0;
      for (; k + 8 <= r1; k += 8) {
        s0 += bf2f(tp[(size_t)(k + 0) * TPSTR + lane]);
        s1 += bf2f(tp[(size_t)(k + 1) * TPSTR + lane]);
        s2 += bf2f(tp[(size_t)(k + 2) * TPSTR + lane]);
        s3 += bf2f(tp[(size_t)(k + 3) * TPSTR + lane]);
        s4 += bf2f(tp[(size_t)(k + 4) * TPSTR + lane]);
        s5 += bf2f(tp[(size_t)(k + 5) * TPSTR + lane]);
        s6 += bf2f(tp[(size_t)(k + 6) * TPSTR + lane]);
        s7 += bf2f(tp[(size_t)(k + 7) * TPSTR + lane]);
      }
      for (; k < r1; ++k) s0 += bf2f(tp[(size_t)k * TPSTR + lane]);
      float s = ((s0 + s1) + (s2 + s3)) + ((s4 + s5) + (s6 + s7));
      float val = s / fmaxf((float)(r1 - r0), 1.f) + nf[(size_t)n * 40 + lane];
      pre[(size_t)n * 40 + lane] = val;
      if (lane < 16) { sacc += val; qacc += val * val; }
      else qacc += val * val;
    }
    if (lane < 16) {
      atomicAdd(&ls[lane], sacc);
      atomicAdd(&ls[16 + lane], qacc);
    } else {
      atomicAdd(&ls[32 + (lane - 16) / 3], qacc);
    }
  }
  __syncthreads();
  if (tid < 40) pstats[(size_t)blockIdx.x * 40 + tid] = ls[tid];
}

// 40 blocks: channel c = blockIdx; sum 625 block-partials
__global__ __launch_bounds__(256) void stats_reduce(
    const float* __restrict__ pstats, float* __restrict__ stats)
{
  const int c = blockIdx.x;
  float s = 0.f;
  for (int i = threadIdx.x; i < GBLK; i += 256) s += pstats[(size_t)i * 40 + c];
#pragma unroll
  for (int off = 1; off < 64; off <<= 1) s += __shfl_xor(s, off);
  __shared__ float red[4];
  if ((threadIdx.x & 63) == 0) red[threadIdx.x >> 6] = s;
  __syncthreads();
  if (threadIdx.x == 0) stats[c] = (red[0] + red[1]) + (red[2] + red[3]);
}

__global__ __launch_bounds__(256) void node_pass2(
    const float* __restrict__ pre, const float* __restrict__ stats,
    const float* __restrict__ bnws, const float* __restrict__ bnbs,
    const float* __restrict__ bnwv, float* __restrict__ out)
{
  int idx = blockIdx.x * blockDim.x + threadIdx.x;
  if (idx >= NN * 40) return;
  int n = idx / 40;
  int c = idx - n * 40;
  float val = pre[idx];
  constexpr float invN = 1.0f / NN;
  if (c < 16) {
    float mu = stats[c] * invN;
    float var = stats[16 + c] * invN - mu * mu;
    out[idx] = (val - mu) * (rsqrtf(var + EPSV) * bnws[c]) + bnbs[c];
  } else {
    int u = (c - 16) / 3;
    float vn = stats[32 + u] * (invN / 3.0f);
    out[idx] = val * (rsqrtf(vn + EPSV) * bnwv[u]);
  }
}

__global__ __launch_bounds__(256) void copy_ef(const f32x4* __restrict__ src,
                                               f32x4* __restrict__ dst) {
  const int n4 = NE * 64 / 4;
  for (int i = blockIdx.x * blockDim.x + threadIdx.x; i < n4;
       i += gridDim.x * blockDim.x)
    dst[i] = src[i];
}

extern "C" void kernel_launch(void* const* d_in, const int* in_sizes, int n_in,
                              void* d_out, int out_size, void* d_ws, size_t ws_size,
                              hipStream_t stream) {
  (void)in_sizes; (void)n_in; (void)out_size;
  const float* nf   = (const float*)d_in[0];
  const float* ef   = (const float*)d_in[1];
  const float* sh   = (const float*)d_in[2];
  const int*   ei   = (const int*)d_in[3];
  const float* w1   = (const float*)d_in[4];
  const float* b1   = (const float*)d_in[5];
  const float* w2   = (const float*)d_in[6];
  const float* b2   = (const float*)d_in[7];
  const float* bnws = (const float*)d_in[8];
  const float* bnbs = (const float*)d_in[9];
  const float* bnwv = (const float*)d_in[10];

  float* out = (float*)d_out;
  float* efout = out + (size_t)NN * 40;

  // ws layout
  char* w = (char*)d_ws;
  int* deg     = (int*)w;                               // NN (zeroed by prep_w2)
  float* stats = (float*)(w + (size_t)NN * 4);          // 40; [44] = b2 flag
  float* flag  = stats + 44;
  int* rowoff  = (int*)(w + (size_t)NN * 4 + 192);      // NN+1
  int* wcur    = rowoff + NN + 1;
  int* perm    = wcur + NN;                             // NE
  float* pre   = (float*)(perm + NE);                   // NN*40
  float* pstats = pre + (size_t)NN * 40;                // GBLK*40
  size_t base  = ((size_t)((char*)(pstats + (size_t)GBLK * 40) - w) + 255) & ~(size_t)255;
  short8* w2bf = (short8*)(w + base);                   // 73728 B
  size_t tpoff = (base + SM_W2 + 255) & ~(size_t)255;

  const size_t TPB = (size_t)NE * TPSTR * 2;            // 20.48 MB (bf16 rows)
  const size_t needA = tpoff + TPB;

  hipFuncSetAttribute((const void*)conv_kernel,
                      hipFuncAttributeMaxDynamicSharedMemorySize, SM_TOTAL);

  prep_w2<<<72 + PREP_DEGB + 1, 64, 0, stream>>>(w2, w2bf, deg, b2, flag);

  const int pblocks = (NN * 40 + 255) / 256;

  hist_kernel<<<625, 256, 0, stream>>>(ei, deg);
  scan_kernel<<<1, 1024, 0, stream>>>(deg, rowoff, wcur);
  fill_kernel<<<625, 256, 0, stream>>>(ei, wcur, perm);

  if (ws_size >= needA) {            // Plan A: tp in ws; ef copy fused in conv
    ushort* tp = (ushort*)(w + tpoff);
    conv_kernel<<<256, 512, SM_TOTAL, stream>>>(
        ef, w1, b1, w2bf, b2, nf, sh, ei, perm, efout, 1, tp, flag);
    gather_kernel<<<GBLK, 256, 0, stream>>>(tp, rowoff, nf, pre, pstats);
    stats_reduce<<<40, 256, 0, stream>>>(pstats, stats);
    node_pass2<<<pblocks, 256, 0, stream>>>(pre, stats, bnws, bnbs, bnwv, out);
  } else {                           // Plan D: tp in efout region; copy ef last
    ushort* tp = (ushort*)efout;                              // 20.48 MB <= 40.9 MB
    conv_kernel<<<256, 512, SM_TOTAL, stream>>>(
        ef, w1, b1, w2bf, b2, nf, sh, ei, perm, efout, 0, tp, flag);
    gather_kernel<<<GBLK, 256, 0, stream>>>(tp, rowoff, nf, pre, pstats);
    stats_reduce<<<40, 256, 0, stream>>>(pstats, stats);
    node_pass2<<<pblocks, 256, 0, stream>>>(pre, stats, bnws, bnbs, bnwv, out);
    copy_ef<<<2048, 256, 0, stream>>>((const f32x4*)ef, (f32x4*)efout);
  }
}